// Round 4
// baseline (900.026 us; speedup 1.0000x reference)
//
#include <hip/hip_runtime.h>

#define EPS_BN 1e-5f
#define BINSHIFT 9
#define BINW 512
#define P_EPB 8192   // edges per block in count/scatter passes
#define LDS_CAP 10240

typedef __attribute__((ext_vector_type(8))) short short8;
typedef __attribute__((ext_vector_type(4))) float f32x4;

__device__ __forceinline__ unsigned short f2bf(float x) {
    unsigned int u = __float_as_uint(x);
    u += 0x7fffu + ((u >> 16) & 1u);
    return (unsigned short)(u >> 16);
}
__device__ __forceinline__ float bf2f(unsigned short h) {
    return __uint_as_float(((unsigned int)h) << 16);
}

// inclusive Hillis-Steele scan over a[0..511], 512 threads
__device__ __forceinline__ void scan512(int* a, int t) {
    for (int off = 1; off < 512; off <<= 1) {
        int v = (t >= off) ? a[t - off] : 0;
        __syncthreads();
        a[t] += v;
        __syncthreads();
    }
}

// ------------------------------------------------ prep: cvt_x | cvt_w | p1_count
__global__ __launch_bounds__(256) void prep_kernel(
    const float* __restrict__ X, unsigned short* __restrict__ Xb, int total4,
    const float* __restrict__ Ws1, const float* __restrict__ Wn1,
    const float* __restrict__ Ws2, const float* __restrict__ Wn2,
    unsigned short* __restrict__ W1f, unsigned short* __restrict__ W2f,
    const int* __restrict__ dst, int* __restrict__ counts, int E, int NB,
    int cvtB, int wB) {
    int tid = threadIdx.x;
    if (blockIdx.x < cvtB) {
        const float4* X4 = (const float4*)X;
        for (int i = blockIdx.x * 256 + tid; i < total4; i += 256 * cvtB) {
            float4 v = X4[i];
            ushort4 o;
            o.x = f2bf(v.x); o.y = f2bf(v.y); o.z = f2bf(v.z); o.w = f2bf(v.w);
            *(ushort4*)&Xb[(size_t)i * 4] = o;
        }
    } else if (blockIdx.x < cvtB + wB) {
        int i = (blockIdx.x - cvtB) * 256 + tid;
        if (i < 128 * 256) {  // W1: MT=256, NCT=16
            int j = i & 7, L = (i >> 3) & 63, c = (i >> 9) & 15, kk = i >> 13;
            int k = kk * 32 + (L >> 4) * 8 + j;
            int col = c * 16 + (L & 15);
            float v = (col < 128) ? Ws1[k * 128 + col] : Wn1[k * 128 + (col - 128)];
            W1f[i] = f2bf(v);
        } else {
            int idx = i - 128 * 256;
            if (idx < 128 * 128) {  // W2: MT=128, NCT=8
                int j = idx & 7, L = (idx >> 3) & 63, c = (idx >> 9) & 7, kk = idx >> 12;
                int k = kk * 32 + (L >> 4) * 8 + j;
                int col = c * 16 + (L & 15);
                float v = (col < 64) ? Ws2[k * 64 + col] : Wn2[k * 64 + (col - 64)];
                W2f[idx] = f2bf(v);
            }
        }
    } else {
        __shared__ int hist[512];
        int blk = blockIdx.x - cvtB - wB;
        int e0 = blk * P_EPB, e1 = min(e0 + P_EPB, E);
        for (int b = tid; b < 512; b += 256) hist[b] = 0;
        __syncthreads();
        for (int e = e0 + tid; e < e1; e += 256) atomicAdd(&hist[dst[e] >> BINSHIFT], 1);
        __syncthreads();
        for (int b = tid; b < NB; b += 256) counts[blk * NB + b] = hist[b];
    }
}

// ------------------------------------------------ p2: bin bases + segment bases
__global__ __launch_bounds__(512) void p2_scan(const int* __restrict__ counts,
                                               int* __restrict__ segbase,
                                               int* __restrict__ binBase, int NB, int NBLK) {
    __shared__ int tot[512];
    int t = threadIdx.x;
    int mytot = 0;
    if (t < NB)
        for (int blk = 0; blk < NBLK; blk++) mytot += counts[blk * NB + t];
    tot[t] = mytot;
    __syncthreads();
    scan512(tot, t);
    int excl = tot[t] - mytot;
    if (t < NB) binBase[t] = excl;
    if (t == NB) binBase[NB] = excl;
    if (t < NB) {
        int run = excl;
        for (int blk = 0; blk < NBLK; blk++) {
            segbase[blk * NB + t] = run;
            run += counts[blk * NB + t];
        }
    }
}

// ------------------------------------------------ p3: LDS-binned scatter of pairs
__global__ __launch_bounds__(512) void p3_scatter(const int* __restrict__ src,
                                                  const int* __restrict__ dst,
                                                  const int* __restrict__ segbase,
                                                  uint2* __restrict__ pairs, int E, int NB) {
    __shared__ uint2 lp[P_EPB];
    __shared__ int hist[512];
    __shared__ int sBase[513];
    __shared__ int cursor[512];
    int t = threadIdx.x;
    int blk = blockIdx.x;
    int e0 = blk * P_EPB, e1 = min(e0 + P_EPB, E), m = e1 - e0;
    hist[t] = 0;
    __syncthreads();
    for (int e = e0 + t; e < e1; e += 512) atomicAdd(&hist[dst[e] >> BINSHIFT], 1);
    __syncthreads();
    int h = hist[t];
    scan512(hist, t);
    int excl = hist[t] - h;
    sBase[t] = excl;
    cursor[t] = excl;
    if (t == 0) sBase[512] = m;
    __syncthreads();
    for (int e = e0 + t; e < e1; e += 512) {
        int d = dst[e];
        int pos = atomicAdd(&cursor[d >> BINSHIFT], 1);
        lp[pos] = make_uint2((unsigned)src[e], (unsigned)d);
    }
    __syncthreads();
    for (int i = t; i < m; i += 512) {
        int lo = 0, hi = NB;
        while (hi - lo > 1) {
            int mid = (lo + hi) >> 1;
            if (sBase[mid] <= i) lo = mid; else hi = mid;
        }
        pairs[segbase[blk * NB + lo] + (i - sBase[lo])] = lp[i];
    }
}

// ------------------------------------------------ p4: per-bin CSR finalize
__global__ __launch_bounds__(512) void p4_csr(const uint2* __restrict__ pairs,
                                              const int* __restrict__ binBase,
                                              int* __restrict__ row_start,
                                              int* __restrict__ cntg,
                                              float* __restrict__ inv_deg,
                                              int* __restrict__ csr_src, int N) {
    __shared__ int ncnt[512];
    __shared__ int cursor[512];
    __shared__ int lsrc[LDS_CAP];
    int t = threadIdx.x;
    int b = blockIdx.x;
    int e0 = binBase[b], e1 = binBase[b + 1], m = e1 - e0;
    int nbase = b << BINSHIFT;
    int nn = min(N - nbase, BINW);
    ncnt[t] = 0;
    __syncthreads();
    for (int i = e0 + t; i < e1; i += 512) atomicAdd(&ncnt[pairs[i].y - nbase], 1);
    __syncthreads();
    int c = ncnt[t];
    scan512(ncnt, t);
    int excl = ncnt[t] - c;
    if (t < nn) {
        int node = nbase + t;
        row_start[node] = e0 + excl;
        cntg[node] = c;
        inv_deg[node] = 1.0f / fmaxf((float)c, 1.0f);
    }
    cursor[t] = excl;
    __syncthreads();
    for (int i = e0 + t; i < e1; i += 512) {
        uint2 p = pairs[i];
        int pos = atomicAdd(&cursor[p.y - nbase], 1);
        if (pos < LDS_CAP) lsrc[pos] = (int)p.x;
    }
    __syncthreads();
    int mm = min(m, LDS_CAP);
    for (int i = t; i < mm; i += 512) csr_src[e0 + i] = lsrc[i];
}

// ---------------------------------------------------------------- dual GEMM (MFMA bf16)
// Y = Xb[N,128] @ Wcat[128,MT]; cols [0,MSELF) -> fp32 row-major Yself,
// cols [MSELF,MT) -> bf16 SLICE-MAJOR YnbS[slice][node][16] for XCD-pinned agg.
// 2 row-tiles per wave: 128 rows/block.
template <int MT, int MSELF>
__global__ __launch_bounds__(256) void gemm_dual(const unsigned short* __restrict__ Xb,
                                                 const unsigned short* __restrict__ Wf,
                                                 float* __restrict__ Yself,
                                                 unsigned short* __restrict__ YnbS, int N) {
    constexpr int K = 128;
    constexpr int NCT = MT / 16;
    constexpr int KS = K / 32;
    __shared__ unsigned short Bl[KS * NCT * 64 * 8];

    for (int i = threadIdx.x; i < KS * NCT * 64; i += 256)
        ((short8*)Bl)[i] = ((const short8*)Wf)[i];
    __syncthreads();

    int wv = threadIdx.x >> 6, lane = threadIdx.x & 63;
    int row0 = blockIdx.x * 128 + wv * 32;
    int m = lane & 15, quad = lane >> 4;

    short8 afrag[2][KS];
#pragma unroll
    for (int t = 0; t < 2; t++) {
        int arow = row0 + t * 16 + m;
        if (arow >= N) arow = N - 1;
        const unsigned short* aptr = Xb + (size_t)arow * K + quad * 8;
#pragma unroll
        for (int kk = 0; kk < KS; kk++) afrag[t][kk] = *(const short8*)(aptr + kk * 32);
    }

    f32x4 acc[2][NCT];
#pragma unroll
    for (int t = 0; t < 2; t++)
        for (int c = 0; c < NCT; c++)
            for (int j = 0; j < 4; j++) acc[t][c][j] = 0.f;

#pragma unroll
    for (int kk = 0; kk < KS; kk++) {
#pragma unroll
        for (int c = 0; c < NCT; c++) {
            short8 bfrag = *(const short8*)&Bl[((kk * NCT + c) * 64 + lane) * 8];
#pragma unroll
            for (int t = 0; t < 2; t++)
                acc[t][c] = __builtin_amdgcn_mfma_f32_16x16x32_bf16(afrag[t][kk], bfrag,
                                                                    acc[t][c], 0, 0, 0);
        }
    }

    // C/D layout: col = lane&15, row = quad*4 + reg
#pragma unroll
    for (int t = 0; t < 2; t++) {
#pragma unroll
        for (int c = 0; c < NCT; c++) {
            int colg = c * 16 + m;
#pragma unroll
            for (int r = 0; r < 4; r++) {
                int row = row0 + t * 16 + quad * 4 + r;
                if (row < N) {
                    float v = acc[t][c][r];
                    if (colg < MSELF)
                        Yself[(size_t)row * MSELF + colg] = v;
                    else {
                        int s = c - MSELF / 16;
                        YnbS[((size_t)s * N + row) * 16 + m] = f2bf(v);
                    }
                }
            }
        }
    }
}

// ------------------------------------------------- XCD-pinned sliced aggregation
// slice = blockIdx.x & (SL-1): round-robin block->XCD dispatch pins each slice's
// 3.2MB gather table into one XCD's L2. Streams (csr, Hself, out) use nontemporal.
// 8 edge-groups x 8 lanes; lane's uint covers 2 bf16 cols; shfl_xor reduce.
template <int M, int SL>
__global__ __launch_bounds__(256) void agg_sliced(const float* Hself,
                                                  const unsigned int* __restrict__ T,
                                                  const int* __restrict__ row_start,
                                                  const int* __restrict__ cnt,
                                                  const float* __restrict__ inv_deg,
                                                  const int* __restrict__ csr_src,
                                                  const float* __restrict__ bias,
                                                  float* out, int N, int nbBlocks) {
    int s = blockIdx.x & (SL - 1);
    int nb = blockIdx.x / SL;
    int wv = threadIdx.x >> 6, L = threadIdx.x & 63;
    int g = L >> 3, c8 = L & 7;
    const unsigned int* Ts = T + (size_t)s * N * 8;
    int stride = nbBlocks * 4;
    for (int n = nb * 4 + wv; n < N; n += stride) {
        int start = row_start[n];
        int ec = cnt[n];
        float inv = inv_deg[n];
        float a0 = 0.f, a1 = 0.f;
        for (int e = g; e < ec; e += 8) {
            int idx = __builtin_nontemporal_load(&csr_src[start + e]);
            unsigned u = Ts[(size_t)idx * 8 + c8];
            a0 += __uint_as_float(u << 16);
            a1 += __uint_as_float(u & 0xffff0000u);
        }
        a0 += __shfl_xor(a0, 8);  a1 += __shfl_xor(a1, 8);
        a0 += __shfl_xor(a0, 16); a1 += __shfl_xor(a1, 16);
        a0 += __shfl_xor(a0, 32); a1 += __shfl_xor(a1, 32);
        if (L < 8) {
            int col = s * 16 + L * 2;
            size_t off = (size_t)n * M + col;
            float hx = __builtin_nontemporal_load(&Hself[off]);
            float hy = __builtin_nontemporal_load(&Hself[off + 1]);
            float ox = hx + a0 * inv + bias[col];
            float oy = hy + a1 * inv + bias[col + 1];
            __builtin_nontemporal_store(ox, &out[off]);
            __builtin_nontemporal_store(oy, &out[off + 1]);
        }
    }
}

// ---------------------------------------------------------------- BatchNorm
template <int M>
__global__ __launch_bounds__(256) void bn_stats(const float* __restrict__ H,
                                                float* __restrict__ sums, int N) {
    int tid = threadIdx.x;
    int c0 = (tid * 4) % M;
    float s[4] = {0.f, 0.f, 0.f, 0.f}, q[4] = {0.f, 0.f, 0.f, 0.f};
    const float4* H4 = (const float4*)H;
    int total4 = N * (M / 4);
    for (int i = blockIdx.x * 256 + tid; i < total4; i += 256 * gridDim.x) {
        float4 v = H4[i];
        s[0] += v.x; q[0] += v.x * v.x;
        s[1] += v.y; q[1] += v.y * v.y;
        s[2] += v.z; q[2] += v.z * v.z;
        s[3] += v.w; q[3] += v.w * v.w;
    }
    __shared__ float red[256 * 8];
    for (int j = 0; j < 4; j++) {
        red[tid * 8 + j] = s[j];
        red[tid * 8 + 4 + j] = q[j];
    }
    __syncthreads();
    constexpr int GRP = M / 4;
    if (tid < GRP) {
        float rs[8] = {0.f, 0.f, 0.f, 0.f, 0.f, 0.f, 0.f, 0.f};
        for (int p = tid; p < 256; p += GRP)
            for (int j = 0; j < 8; j++) rs[j] += red[p * 8 + j];
        for (int j = 0; j < 4; j++) {
            atomicAdd(&sums[c0 + j], rs[j]);
            atomicAdd(&sums[M + c0 + j], rs[4 + j]);
        }
    }
}

// layer-1 apply (finalize folded): fp32 in -> BN+ReLU -> bf16 out
__global__ __launch_bounds__(256) void bn_apply_bf128(const float* __restrict__ H,
                                                      const float* __restrict__ sums,
                                                      const float* __restrict__ gamma,
                                                      const float* __restrict__ beta,
                                                      unsigned short* __restrict__ O,
                                                      int N, float invN) {
    __shared__ float ss[256];
    int tid = threadIdx.x;
    if (tid < 128) {
        float mu = sums[tid] * invN;
        float var = sums[128 + tid] * invN - mu * mu;
        float sc = gamma[tid] * rsqrtf(var + EPS_BN);
        ss[tid] = sc;
        ss[128 + tid] = beta[tid] - mu * sc;
    }
    __syncthreads();
    int total4 = N * 32;
    const float4* H4 = (const float4*)H;
    for (int i = blockIdx.x * 256 + tid; i < total4; i += 256 * gridDim.x) {
        int c0 = (i * 4) & 127;
        float4 v = H4[i];
        float4 sc = *(const float4*)&ss[c0];
        float4 sh = *(const float4*)&ss[128 + c0];
        ushort4 o;
        o.x = f2bf(fmaxf(v.x * sc.x + sh.x, 0.f));
        o.y = f2bf(fmaxf(v.y * sc.y + sh.y, 0.f));
        o.z = f2bf(fmaxf(v.z * sc.z + sh.z, 0.f));
        o.w = f2bf(fmaxf(v.w * sc.w + sh.w, 0.f));
        *(ushort4*)&O[(size_t)i * 4] = o;
    }
}

// layer-2 apply (finalize folded): fp32 in-place, no ReLU
__global__ __launch_bounds__(256) void bn_apply_f64(float* H, const float* __restrict__ sums,
                                                    const float* __restrict__ gamma,
                                                    const float* __restrict__ beta,
                                                    int N, float invN) {
    __shared__ float ss[128];
    int tid = threadIdx.x;
    if (tid < 64) {
        float mu = sums[tid] * invN;
        float var = sums[64 + tid] * invN - mu * mu;
        float sc = gamma[tid] * rsqrtf(var + EPS_BN);
        ss[tid] = sc;
        ss[64 + tid] = beta[tid] - mu * sc;
    }
    __syncthreads();
    int total4 = N * 16;
    float4* H4 = (float4*)H;
    for (int i = blockIdx.x * 256 + threadIdx.x; i < total4; i += 256 * gridDim.x) {
        int c0 = (i * 4) & 63;
        float4 v = H4[i];
        float4 sc = *(const float4*)&ss[c0];
        float4 sh = *(const float4*)&ss[64 + c0];
        v.x = v.x * sc.x + sh.x;
        v.y = v.y * sc.y + sh.y;
        v.z = v.z * sc.z + sh.z;
        v.w = v.w * sc.w + sh.w;
        H4[i] = v;
    }
}

// ---------------------------------------------------------------- launch
extern "C" void kernel_launch(void* const* d_in, const int* in_sizes, int n_in,
                              void* d_out, int out_size, void* d_ws, size_t ws_size,
                              hipStream_t stream) {
    const float* X = (const float*)d_in[0];
    const int* src = (const int*)d_in[1];
    const int* dst = (const int*)d_in[2];
    const float* Wself1 = (const float*)d_in[3];
    const float* Wneigh1 = (const float*)d_in[4];
    const float* b1 = (const float*)d_in[5];
    const float* g1 = (const float*)d_in[6];
    const float* be1 = (const float*)d_in[7];
    const float* Wself2 = (const float*)d_in[8];
    const float* Wneigh2 = (const float*)d_in[9];
    const float* b2 = (const float*)d_in[10];
    const float* g2 = (const float*)d_in[11];
    const float* be2 = (const float*)d_in[12];
    float* out = (float*)d_out;

    const int N = in_sizes[0] / 128;
    const int E = in_sizes[1];
    const int NB = (N + BINW - 1) >> BINSHIFT;    // 196
    const int NBLK = (E + P_EPB - 1) / P_EPB;     // 196

    char* p = (char*)d_ws;
    auto carve = [&](size_t bytes) {
        char* r = p;
        p += (bytes + 255) & ~(size_t)255;
        return r;
    };
    float* sums1 = (float*)carve(256 * 4);
    float* sums2 = (float*)carve(128 * 4);
    size_t zero_bytes = (size_t)(p - (char*)d_ws);
    int* counts = (int*)carve((size_t)NBLK * NB * 4);
    int* segbase = (int*)carve((size_t)NBLK * NB * 4);
    int* binBase = (int*)carve((size_t)(NB + 1) * 4);
    uint2* pairs = (uint2*)carve((size_t)E * 8);
    int* csr_src = (int*)carve((size_t)E * 4);
    int* row_start = (int*)carve((size_t)N * 4);
    int* cntg = (int*)carve((size_t)N * 4);
    float* inv_deg = (float*)carve((size_t)N * 4);
    unsigned short* W1f = (unsigned short*)carve(128 * 256 * 2);
    unsigned short* W2f = (unsigned short*)carve(128 * 128 * 2);
    float* bufA = (float*)carve((size_t)N * 128 * 4);
    unsigned short* Xb = (unsigned short*)carve((size_t)N * 128 * 2);   // also h1b
    unsigned short* tab = (unsigned short*)carve((size_t)N * 128 * 2);  // slice-major

    hipMemsetAsync(d_ws, 0, zero_bytes, stream);

    const int cvtB = 1024, wB = 192;
    prep_kernel<<<cvtB + wB + NBLK, 256, 0, stream>>>(X, Xb, N * 32, Wself1, Wneigh1,
                                                      Wself2, Wneigh2, W1f, W2f, dst,
                                                      counts, E, NB, cvtB, wB);
    p2_scan<<<1, 512, 0, stream>>>(counts, segbase, binBase, NB, NBLK);
    p3_scatter<<<NBLK, 512, 0, stream>>>(src, dst, segbase, pairs, E, NB);
    p4_csr<<<NB, 512, 0, stream>>>(pairs, binBase, row_start, cntg, inv_deg, csr_src, N);

    int ggrid = (N + 127) / 128;
    // ---- layer 1 (128 -> 128)
    gemm_dual<256, 128><<<ggrid, 256, 0, stream>>>(Xb, W1f, bufA, tab, N);
    agg_sliced<128, 8><<<8 * 1024, 256, 0, stream>>>(bufA, (const unsigned int*)tab,
                                                     row_start, cntg, inv_deg, csr_src,
                                                     b1, bufA, N, 1024);
    bn_stats<128><<<256, 256, 0, stream>>>(bufA, sums1, N);
    bn_apply_bf128<<<2048, 256, 0, stream>>>(bufA, sums1, g1, be1, Xb, N, 1.0f / (float)N);

    // ---- layer 2 (128 -> 64)
    gemm_dual<128, 64><<<ggrid, 256, 0, stream>>>(Xb, W2f, out, tab, N);
    agg_sliced<64, 4><<<4 * 2048, 256, 0, stream>>>(out, (const unsigned int*)tab,
                                                    row_start, cntg, inv_deg, csr_src,
                                                    b2, out, N, 2048);
    bn_stats<64><<<256, 256, 0, stream>>>(out, sums2, N);
    bn_apply_f64<<<2048, 256, 0, stream>>>(out, sums2, g2, be2, N, 1.0f / (float)N);
}

// Round 6
// 596.251 us; speedup vs baseline: 1.5095x; 1.5095x over previous
//
#include <hip/hip_runtime.h>

#define EPS_BN 1e-5f
#define BINSHIFT 9
#define BINW 512
#define P_EPB 8192   // edges per block in count/scatter passes
#define LDS_CAP 10240

typedef __attribute__((ext_vector_type(8))) short short8;
typedef __attribute__((ext_vector_type(4))) float f32x4;
typedef __attribute__((ext_vector_type(2))) float f32x2;

__device__ __forceinline__ unsigned short f2bf(float x) {
    unsigned int u = __float_as_uint(x);
    u += 0x7fffu + ((u >> 16) & 1u);
    return (unsigned short)(u >> 16);
}
__device__ __forceinline__ float bf2f(unsigned short h) {
    return __uint_as_float(((unsigned int)h) << 16);
}
__device__ __forceinline__ float bflo(unsigned u) { return __uint_as_float(u << 16); }
__device__ __forceinline__ float bfhi(unsigned u) { return __uint_as_float(u & 0xffff0000u); }

// inclusive scans (all threads of the block must enter)
__device__ __forceinline__ void scan512(int* a, int t) {
    for (int off = 1; off < 512; off <<= 1) {
        int v = (t >= off) ? a[t - off] : 0;
        __syncthreads();
        a[t] += v;
        __syncthreads();
    }
}
__device__ __forceinline__ void scan256(int* a, int t) {
    for (int off = 1; off < 256; off <<= 1) {
        int v = (t >= off) ? a[t - off] : 0;
        __syncthreads();
        a[t] += v;
        __syncthreads();
    }
}

// ------------------------------------------------ prep: cvt_x | cvt_w | p1_count
__global__ __launch_bounds__(256) void prep_kernel(
    const float* __restrict__ X, unsigned short* __restrict__ Xb, int total4,
    const float* __restrict__ Ws1, const float* __restrict__ Wn1,
    const float* __restrict__ Ws2, const float* __restrict__ Wn2,
    unsigned short* __restrict__ W1f, unsigned short* __restrict__ W2f,
    const int* __restrict__ dst, int* __restrict__ counts, int E, int NB,
    int cvtB, int wB) {
    int tid = threadIdx.x;
    if (blockIdx.x < cvtB) {
        const float4* X4 = (const float4*)X;
        for (int i = blockIdx.x * 256 + tid; i < total4; i += 256 * cvtB) {
            float4 v = X4[i];
            ushort4 o;
            o.x = f2bf(v.x); o.y = f2bf(v.y); o.z = f2bf(v.z); o.w = f2bf(v.w);
            *(ushort4*)&Xb[(size_t)i * 4] = o;
        }
    } else if (blockIdx.x < cvtB + wB) {
        int i = (blockIdx.x - cvtB) * 256 + tid;
        if (i < 128 * 256) {  // W1: MT=256, NCT=16
            int j = i & 7, L = (i >> 3) & 63, c = (i >> 9) & 15, kk = i >> 13;
            int k = kk * 32 + (L >> 4) * 8 + j;
            int col = c * 16 + (L & 15);
            float v = (col < 128) ? Ws1[k * 128 + col] : Wn1[k * 128 + (col - 128)];
            W1f[i] = f2bf(v);
        } else {
            int idx = i - 128 * 256;
            if (idx < 128 * 128) {  // W2: MT=128, NCT=8
                int j = idx & 7, L = (idx >> 3) & 63, c = (idx >> 9) & 7, kk = idx >> 12;
                int k = kk * 32 + (L >> 4) * 8 + j;
                int col = c * 16 + (L & 15);
                float v = (col < 64) ? Ws2[k * 64 + col] : Wn2[k * 64 + (col - 64)];
                W2f[idx] = f2bf(v);
            }
        }
    } else {
        __shared__ int hist[512];
        int blk = blockIdx.x - cvtB - wB;
        int e0 = blk * P_EPB, e1 = min(e0 + P_EPB, E);
        for (int b = tid; b < 512; b += 256) hist[b] = 0;
        __syncthreads();
        for (int e = e0 + tid; e < e1; e += 256) atomicAdd(&hist[dst[e] >> BINSHIFT], 1);
        __syncthreads();
        for (int b = tid; b < NB; b += 256) counts[blk * NB + b] = hist[b];
    }
}

// ------------------------------------------------ p2a: per-bin scan over edge-blocks
__global__ __launch_bounds__(256) void p2a(const int* __restrict__ counts,
                                           int* __restrict__ segrel,
                                           int* __restrict__ tot, int NB, int NBLK) {
    __shared__ int s[256];
    int b = blockIdx.x, t = threadIdx.x;
    int v = (t < NBLK) ? counts[t * NB + b] : 0;
    s[t] = v;
    __syncthreads();
    scan256(s, t);
    if (t < NBLK) segrel[t * NB + b] = s[t] - v;
    if (t == 255) tot[b] = s[255];
}

// ------------------------------------------------ p2b: bin bases
__global__ __launch_bounds__(256) void p2b(const int* __restrict__ tot,
                                           int* __restrict__ binBase, int NB, int E) {
    __shared__ int s[256];
    int t = threadIdx.x;
    int v = (t < NB) ? tot[t] : 0;
    s[t] = v;
    __syncthreads();
    scan256(s, t);
    if (t < NB) binBase[t] = s[t] - v;
    if (t == 0) binBase[NB] = E;
}

// ------------------------------------------------ p3: LDS-binned scatter of pairs
__global__ __launch_bounds__(512) void p3_scatter(const int* __restrict__ src,
                                                  const int* __restrict__ dst,
                                                  const int* __restrict__ segrel,
                                                  const int* __restrict__ binBase,
                                                  uint2* __restrict__ pairs, int E, int NB) {
    __shared__ uint2 lp[P_EPB];
    __shared__ int hist[512];
    __shared__ int sBase[513];
    __shared__ int cursor[512];
    int t = threadIdx.x;
    int blk = blockIdx.x;
    int e0 = blk * P_EPB, e1 = min(e0 + P_EPB, E), m = e1 - e0;
    hist[t] = 0;
    __syncthreads();
    for (int e = e0 + t; e < e1; e += 512) atomicAdd(&hist[dst[e] >> BINSHIFT], 1);
    __syncthreads();
    int h = hist[t];
    scan512(hist, t);
    int excl = hist[t] - h;
    sBase[t] = excl;
    cursor[t] = excl;
    if (t == 0) sBase[512] = m;
    __syncthreads();
    for (int e = e0 + t; e < e1; e += 512) {
        int d = dst[e];
        int pos = atomicAdd(&cursor[d >> BINSHIFT], 1);
        lp[pos] = make_uint2((unsigned)src[e], (unsigned)d);
    }
    __syncthreads();
    for (int i = t; i < m; i += 512) {
        int lo = 0, hi = NB;
        while (hi - lo > 1) {
            int mid = (lo + hi) >> 1;
            if (sBase[mid] <= i) lo = mid; else hi = mid;
        }
        pairs[binBase[lo] + segrel[blk * NB + lo] + (i - sBase[lo])] = lp[i];
    }
}

// ------------------------------------------------ p4: per-bin CSR finalize
__global__ __launch_bounds__(512) void p4_csr(const uint2* __restrict__ pairs,
                                              const int* __restrict__ binBase,
                                              int* __restrict__ row_start,
                                              int* __restrict__ cntg,
                                              float* __restrict__ inv_deg,
                                              int* __restrict__ csr_src, int N) {
    __shared__ int ncnt[512];
    __shared__ int cursor[512];
    __shared__ int lsrc[LDS_CAP];
    int t = threadIdx.x;
    int b = blockIdx.x;
    int e0 = binBase[b], e1 = binBase[b + 1], m = e1 - e0;
    int nbase = b << BINSHIFT;
    int nn = min(N - nbase, BINW);
    ncnt[t] = 0;
    __syncthreads();
    for (int i = e0 + t; i < e1; i += 512) atomicAdd(&ncnt[pairs[i].y - nbase], 1);
    __syncthreads();
    int c = ncnt[t];
    scan512(ncnt, t);
    int excl = ncnt[t] - c;
    if (t < nn) {
        int node = nbase + t;
        row_start[node] = e0 + excl;
        cntg[node] = c;
        inv_deg[node] = 1.0f / fmaxf((float)c, 1.0f);
    }
    cursor[t] = excl;
    __syncthreads();
    for (int i = e0 + t; i < e1; i += 512) {
        uint2 p = pairs[i];
        int pos = atomicAdd(&cursor[p.y - nbase], 1);
        if (pos < LDS_CAP) lsrc[pos] = (int)p.x;
    }
    __syncthreads();
    int mm = min(m, LDS_CAP);
    for (int i = t; i < mm; i += 512) csr_src[e0 + i] = lsrc[i];
}

// ---------------------------------------------------------------- dual GEMM (MFMA bf16)
// Y = A[N,128] @ Wcat[128,MT].
//  cols [0,MSELF)   -> self output: bf16 row-major (SELFBF) or fp32 row-major
//  cols [MSELF,MT)  -> bf16 slice-major YnbS[slice][node][16] (16-col slices)
// FUSEBN: A = BN+ReLU applied on-the-fly per input column from sums/gamma/beta.
template <int MT, int MSELF, bool SELFBF, bool FUSEBN>
__global__ __launch_bounds__(256) void gemm_dual(const unsigned short* __restrict__ A,
                                                 const unsigned short* __restrict__ Wf,
                                                 float* __restrict__ YselfF,
                                                 unsigned short* __restrict__ YselfB,
                                                 unsigned short* __restrict__ YnbS, int N,
                                                 const float* __restrict__ sums,
                                                 const float* __restrict__ gamma,
                                                 const float* __restrict__ beta,
                                                 float invN) {
    constexpr int K = 128;
    constexpr int NCT = MT / 16;
    constexpr int KS = K / 32;
    __shared__ unsigned short Bl[KS * NCT * 64 * 8];
    __shared__ float ssc[128], ssh[128];

    for (int i = threadIdx.x; i < KS * NCT * 64; i += 256)
        ((short8*)Bl)[i] = ((const short8*)Wf)[i];
    if (FUSEBN && threadIdx.x < 128) {
        int c = threadIdx.x;
        float mu = sums[c] * invN;
        float var = sums[128 + c] * invN - mu * mu;
        float sc = gamma[c] * rsqrtf(var + EPS_BN);
        ssc[c] = sc;
        ssh[c] = beta[c] - mu * sc;
    }
    __syncthreads();

    int wv = threadIdx.x >> 6, lane = threadIdx.x & 63;
    int row0 = blockIdx.x * 128 + wv * 32;
    int m = lane & 15, quad = lane >> 4;

    short8 afrag[2][KS];
#pragma unroll
    for (int t = 0; t < 2; t++) {
        int arow = row0 + t * 16 + m;
        if (arow >= N) arow = N - 1;
        const unsigned short* aptr = A + (size_t)arow * K + quad * 8;
#pragma unroll
        for (int kk = 0; kk < KS; kk++) {
            short8 raw = *(const short8*)(aptr + kk * 32);
            if (FUSEBN) {
#pragma unroll
                for (int j = 0; j < 8; j++) {
                    int c = kk * 32 + quad * 8 + j;
                    float f = bf2f((unsigned short)raw[j]) * ssc[c] + ssh[c];
                    raw[j] = (short)f2bf(fmaxf(f, 0.f));
                }
            }
            afrag[t][kk] = raw;
        }
    }

    f32x4 acc[2][NCT];
#pragma unroll
    for (int t = 0; t < 2; t++)
        for (int c = 0; c < NCT; c++)
            for (int j = 0; j < 4; j++) acc[t][c][j] = 0.f;

#pragma unroll
    for (int kk = 0; kk < KS; kk++) {
#pragma unroll
        for (int c = 0; c < NCT; c++) {
            short8 bfrag = *(const short8*)&Bl[((kk * NCT + c) * 64 + lane) * 8];
#pragma unroll
            for (int t = 0; t < 2; t++)
                acc[t][c] = __builtin_amdgcn_mfma_f32_16x16x32_bf16(afrag[t][kk], bfrag,
                                                                    acc[t][c], 0, 0, 0);
        }
    }

    // C/D layout: col = lane&15, row = quad*4 + reg
#pragma unroll
    for (int t = 0; t < 2; t++) {
#pragma unroll
        for (int c = 0; c < NCT; c++) {
            int colg = c * 16 + m;
#pragma unroll
            for (int r = 0; r < 4; r++) {
                int row = row0 + t * 16 + quad * 4 + r;
                if (row < N) {
                    float v = acc[t][c][r];
                    if (colg < MSELF) {
                        if (SELFBF)
                            YselfB[(size_t)row * MSELF + colg] = f2bf(v);
                        else
                            YselfF[(size_t)row * MSELF + colg] = v;
                    } else {
                        int s = c - MSELF / 16;
                        YnbS[((size_t)s * N + row) * 16 + m] = f2bf(v);
                    }
                }
            }
        }
    }
}

// ------------------------------------------------- XCD-pinned sliced aggregation
// One 8-lane group per (node, slice); 8 independent nodes per wave; 4-edge unroll
// -> 8 groups x 4 edges x 32B = 1KB in flight per wave. No cross-lane reduce:
// group g owns 16 output cols of its node. slice = blockIdx%SL rides the
// round-robin block->XCD dispatch so each XCD's L2 holds one 3.2MB table slice.
template <int M, int SL, bool OUTBF>
__global__ __launch_bounds__(256) void agg_slice(const void* __restrict__ SelfV,
                                                 const unsigned int* __restrict__ T,
                                                 const int* __restrict__ row_start,
                                                 const int* __restrict__ cnt,
                                                 const float* __restrict__ inv_deg,
                                                 const int* __restrict__ csr_src,
                                                 const float* __restrict__ bias,
                                                 void* __restrict__ OutV, int N) {
    int s = blockIdx.x & (SL - 1);
    int ng = blockIdx.x / SL;
    int wv = threadIdx.x >> 6, L = threadIdx.x & 63;
    int g = L >> 3, c8 = L & 7;
    int n = (ng * 4 + wv) * 8 + g;
    if (n >= N) return;
    int start = __builtin_nontemporal_load(&row_start[n]);
    int ec = __builtin_nontemporal_load(&cnt[n]);
    float inv = __builtin_nontemporal_load(&inv_deg[n]);
    const unsigned int* Ts = T + (size_t)s * N * 8;
    float a0 = 0.f, a1 = 0.f;
    int e = 0;
    for (; e + 3 < ec; e += 4) {
        int i0 = __builtin_nontemporal_load(&csr_src[start + e]);
        int i1 = __builtin_nontemporal_load(&csr_src[start + e + 1]);
        int i2 = __builtin_nontemporal_load(&csr_src[start + e + 2]);
        int i3 = __builtin_nontemporal_load(&csr_src[start + e + 3]);
        unsigned u0 = Ts[(size_t)i0 * 8 + c8];
        unsigned u1 = Ts[(size_t)i1 * 8 + c8];
        unsigned u2 = Ts[(size_t)i2 * 8 + c8];
        unsigned u3 = Ts[(size_t)i3 * 8 + c8];
        a0 += bflo(u0) + bflo(u1) + bflo(u2) + bflo(u3);
        a1 += bfhi(u0) + bfhi(u1) + bfhi(u2) + bfhi(u3);
    }
    for (; e < ec; e++) {
        int i0 = __builtin_nontemporal_load(&csr_src[start + e]);
        unsigned u0 = Ts[(size_t)i0 * 8 + c8];
        a0 += bflo(u0);
        a1 += bfhi(u0);
    }
    int col = s * 16 + c8 * 2;
    float b0 = bias[col], b1v = bias[col + 1];
    if (OUTBF) {
        const unsigned short* Sb = (const unsigned short*)SelfV;
        unsigned su =
            __builtin_nontemporal_load((const unsigned int*)(Sb + (size_t)n * M + col));
        float h0 = bflo(su) + a0 * inv + b0;
        float h1 = bfhi(su) + a1 * inv + b1v;
        unsigned o = (unsigned)f2bf(h0) | ((unsigned)f2bf(h1) << 16);
        __builtin_nontemporal_store(o,
            (unsigned int*)((unsigned short*)OutV + (size_t)n * M + col));
    } else {
        const float* Sf = (const float*)SelfV;
        f32x2 sv = __builtin_nontemporal_load((const f32x2*)(Sf + (size_t)n * M + col));
        f32x2 o;
        o.x = sv.x + a0 * inv + b0;
        o.y = sv.y + a1 * inv + b1v;
        __builtin_nontemporal_store(o, (f32x2*)((float*)OutV + (size_t)n * M + col));
    }
}

// ---------------------------------------------------------------- BatchNorm stats
// bf16 input, M=128: thread handles 8 consecutive cols (uint4 = 8 bf16)
__global__ __launch_bounds__(256) void bn_stats_bf128(const unsigned short* __restrict__ H,
                                                      float* __restrict__ sums, int N) {
    int tid = threadIdx.x;
    float s[8] = {0, 0, 0, 0, 0, 0, 0, 0}, q[8] = {0, 0, 0, 0, 0, 0, 0, 0};
    const uint4* H8 = (const uint4*)H;
    int total8 = N * 16;
    for (int i = blockIdx.x * 256 + tid; i < total8; i += 256 * gridDim.x) {
        uint4 v = H8[i];
        unsigned w[4] = {v.x, v.y, v.z, v.w};
#pragma unroll
        for (int j = 0; j < 4; j++) {
            float f0 = bflo(w[j]), f1 = bfhi(w[j]);
            s[2 * j] += f0; q[2 * j] += f0 * f0;
            s[2 * j + 1] += f1; q[2 * j + 1] += f1 * f1;
        }
    }
    __shared__ float red[256 * 16];
    for (int j = 0; j < 8; j++) {
        red[tid * 16 + j] = s[j];
        red[tid * 16 + 8 + j] = q[j];
    }
    __syncthreads();
    if (tid < 16) {
        float rs[16];
        for (int j = 0; j < 16; j++) rs[j] = 0.f;
        for (int p = tid; p < 256; p += 16)
            for (int j = 0; j < 16; j++) rs[j] += red[p * 16 + j];
        int cc = tid * 8;
        for (int j = 0; j < 8; j++) {
            atomicAdd(&sums[cc + j], rs[j]);
            atomicAdd(&sums[128 + cc + j], rs[8 + j]);
        }
    }
}

// fp32 input (layer-2 output in d_out)
template <int M>
__global__ __launch_bounds__(256) void bn_stats(const float* __restrict__ H,
                                                float* __restrict__ sums, int N) {
    int tid = threadIdx.x;
    int c0 = (tid * 4) % M;
    float s[4] = {0.f, 0.f, 0.f, 0.f}, q[4] = {0.f, 0.f, 0.f, 0.f};
    const float4* H4 = (const float4*)H;
    int total4 = N * (M / 4);
    for (int i = blockIdx.x * 256 + tid; i < total4; i += 256 * gridDim.x) {
        float4 v = H4[i];
        s[0] += v.x; q[0] += v.x * v.x;
        s[1] += v.y; q[1] += v.y * v.y;
        s[2] += v.z; q[2] += v.z * v.z;
        s[3] += v.w; q[3] += v.w * v.w;
    }
    __shared__ float red[256 * 8];
    for (int j = 0; j < 4; j++) {
        red[tid * 8 + j] = s[j];
        red[tid * 8 + 4 + j] = q[j];
    }
    __syncthreads();
    constexpr int GRP = M / 4;
    if (tid < GRP) {
        float rs[8] = {0.f, 0.f, 0.f, 0.f, 0.f, 0.f, 0.f, 0.f};
        for (int p = tid; p < 256; p += GRP)
            for (int j = 0; j < 8; j++) rs[j] += red[p * 8 + j];
        for (int j = 0; j < 4; j++) {
            atomicAdd(&sums[c0 + j], rs[j]);
            atomicAdd(&sums[M + c0 + j], rs[4 + j]);
        }
    }
}

// layer-2 apply (finalize folded): fp32 in-place, no ReLU
__global__ __launch_bounds__(256) void bn_apply_f64(float* H, const float* __restrict__ sums,
                                                    const float* __restrict__ gamma,
                                                    const float* __restrict__ beta,
                                                    int N, float invN) {
    __shared__ float ss[128];
    int tid = threadIdx.x;
    if (tid < 64) {
        float mu = sums[tid] * invN;
        float var = sums[64 + tid] * invN - mu * mu;
        float sc = gamma[tid] * rsqrtf(var + EPS_BN);
        ss[tid] = sc;
        ss[64 + tid] = beta[tid] - mu * sc;
    }
    __syncthreads();
    int total4 = N * 16;
    float4* H4 = (float4*)H;
    for (int i = blockIdx.x * 256 + threadIdx.x; i < total4; i += 256 * gridDim.x) {
        int c0 = (i * 4) & 63;
        float4 v = H4[i];
        float4 sc = *(const float4*)&ss[c0];
        float4 sh = *(const float4*)&ss[64 + c0];
        v.x = v.x * sc.x + sh.x;
        v.y = v.y * sc.y + sh.y;
        v.z = v.z * sc.z + sh.z;
        v.w = v.w * sc.w + sh.w;
        H4[i] = v;
    }
}

// ---------------------------------------------------------------- launch
extern "C" void kernel_launch(void* const* d_in, const int* in_sizes, int n_in,
                              void* d_out, int out_size, void* d_ws, size_t ws_size,
                              hipStream_t stream) {
    const float* X = (const float*)d_in[0];
    const int* src = (const int*)d_in[1];
    const int* dst = (const int*)d_in[2];
    const float* Wself1 = (const float*)d_in[3];
    const float* Wneigh1 = (const float*)d_in[4];
    const float* b1 = (const float*)d_in[5];
    const float* g1 = (const float*)d_in[6];
    const float* be1 = (const float*)d_in[7];
    const float* Wself2 = (const float*)d_in[8];
    const float* Wneigh2 = (const float*)d_in[9];
    const float* b2 = (const float*)d_in[10];
    const float* g2 = (const float*)d_in[11];
    const float* be2 = (const float*)d_in[12];
    float* out = (float*)d_out;

    const int N = in_sizes[0] / 128;
    const int E = in_sizes[1];
    const int NB = (N + BINW - 1) >> BINSHIFT;    // 196
    const int NBLK = (E + P_EPB - 1) / P_EPB;     // 196 (<=256 required by p2a)

    char* p = (char*)d_ws;
    auto carve = [&](size_t bytes) {
        char* r = p;
        p += (bytes + 255) & ~(size_t)255;
        return r;
    };
    float* sums1 = (float*)carve(256 * 4);
    float* sums2 = (float*)carve(128 * 4);
    size_t zero_bytes = (size_t)(p - (char*)d_ws);
    int* counts = (int*)carve((size_t)NBLK * NB * 4);
    int* segrel = (int*)carve((size_t)NBLK * NB * 4);
    int* tot = (int*)carve((size_t)NB * 4);
    int* binBase = (int*)carve((size_t)(NB + 1) * 4);
    uint2* pairs = (uint2*)carve((size_t)E * 8);
    int* csr_src = (int*)carve((size_t)E * 4);
    int* row_start = (int*)carve((size_t)N * 4);
    int* cntg = (int*)carve((size_t)N * 4);
    float* inv_deg = (float*)carve((size_t)N * 4);
    unsigned short* W1f = (unsigned short*)carve(128 * 256 * 2);
    unsigned short* W2f = (unsigned short*)carve(128 * 128 * 2);
    unsigned short* Xb = (unsigned short*)carve((size_t)N * 128 * 2);
    unsigned short* bufS = (unsigned short*)carve((size_t)N * 128 * 2);  // self1 bf16
    unsigned short* tab = (unsigned short*)carve((size_t)N * 128 * 2);   // slice-major
    unsigned short* h1b = (unsigned short*)carve((size_t)N * 128 * 2);   // h1 pre-BN bf16

    hipMemsetAsync(d_ws, 0, zero_bytes, stream);

    const int cvtB = 1024, wB = 192;
    const float invN = 1.0f / (float)N;
    prep_kernel<<<cvtB + wB + NBLK, 256, 0, stream>>>(X, Xb, N * 32, Wself1, Wneigh1,
                                                      Wself2, Wneigh2, W1f, W2f, dst,
                                                      counts, E, NB, cvtB, wB);
    p2a<<<NB, 256, 0, stream>>>(counts, segrel, tot, NB, NBLK);
    p2b<<<1, 256, 0, stream>>>(tot, binBase, NB, E);
    p3_scatter<<<NBLK, 512, 0, stream>>>(src, dst, segrel, binBase, pairs, E, NB);
    p4_csr<<<NB, 512, 0, stream>>>(pairs, binBase, row_start, cntg, inv_deg, csr_src, N);

    int ggrid = (N + 127) / 128;
    // ---- layer 1 (128 -> 128): self bf16 -> bufS, neigh bf16 slice-major -> tab
    gemm_dual<256, 128, true, false><<<ggrid, 256, 0, stream>>>(
        Xb, W1f, nullptr, bufS, tab, N, nullptr, nullptr, nullptr, 0.f);
    agg_slice<128, 8, true><<<8 * ((N + 31) / 32), 256, 0, stream>>>(
        bufS, (const unsigned int*)tab, row_start, cntg, inv_deg, csr_src, b1, h1b, N);
    bn_stats_bf128<<<256, 256, 0, stream>>>(h1b, sums1, N);

    // ---- layer 2 (128 -> 64): BN1+ReLU fused into A-load; self fp32 -> out
    gemm_dual<128, 64, false, true><<<ggrid, 256, 0, stream>>>(
        h1b, W2f, out, nullptr, tab, N, sums1, g1, be1, invN);
    agg_slice<64, 4, false><<<4 * ((N + 31) / 32), 256, 0, stream>>>(
        out, (const unsigned int*)tab, row_start, cntg, inv_deg, csr_src, b2, out, N);
    bn_stats<64><<<256, 256, 0, stream>>>(out, sums2, N);
    bn_apply_f64<<<2048, 256, 0, stream>>>(out, sums2, g2, be2, N, invN);
}

// Round 7
// 435.607 us; speedup vs baseline: 2.0661x; 1.3688x over previous
//
#include <hip/hip_runtime.h>

#define EPS_BN 1e-5f
#define BINSHIFT 9
#define BINW 512
#define P_EPB 8192   // edges per block in count/scatter passes
#define LDS_CAP 10240

typedef __attribute__((ext_vector_type(8))) short short8;
typedef __attribute__((ext_vector_type(4))) float f32x4;

__device__ __forceinline__ unsigned short f2bf(float x) {
    unsigned int u = __float_as_uint(x);
    u += 0x7fffu + ((u >> 16) & 1u);
    return (unsigned short)(u >> 16);
}
__device__ __forceinline__ float bf2f(unsigned short h) {
    return __uint_as_float(((unsigned int)h) << 16);
}
__device__ __forceinline__ float bflo(unsigned u) { return __uint_as_float(u << 16); }
__device__ __forceinline__ float bfhi(unsigned u) { return __uint_as_float(u & 0xffff0000u); }

// inclusive scans (all threads of the block must enter)
__device__ __forceinline__ void scan512(int* a, int t) {
    for (int off = 1; off < 512; off <<= 1) {
        int v = (t >= off) ? a[t - off] : 0;
        __syncthreads();
        a[t] += v;
        __syncthreads();
    }
}
__device__ __forceinline__ void scan256(int* a, int t) {
    for (int off = 1; off < 256; off <<= 1) {
        int v = (t >= off) ? a[t - off] : 0;
        __syncthreads();
        a[t] += v;
        __syncthreads();
    }
}

// ------------------------------------------------ prep: cvt_x | cvt_w | p1_count
__global__ __launch_bounds__(256) void prep_kernel(
    const float* __restrict__ X, unsigned short* __restrict__ Xb, int total4,
    const float* __restrict__ Ws1, const float* __restrict__ Wn1,
    const float* __restrict__ Ws2, const float* __restrict__ Wn2,
    unsigned short* __restrict__ W1f, unsigned short* __restrict__ W2f,
    const int* __restrict__ dst, int* __restrict__ counts, int E, int NB,
    int cvtB, int wB) {
    int tid = threadIdx.x;
    if (blockIdx.x < cvtB) {
        const float4* X4 = (const float4*)X;
        for (int i = blockIdx.x * 256 + tid; i < total4; i += 256 * cvtB) {
            float4 v = X4[i];
            ushort4 o;
            o.x = f2bf(v.x); o.y = f2bf(v.y); o.z = f2bf(v.z); o.w = f2bf(v.w);
            *(ushort4*)&Xb[(size_t)i * 4] = o;
        }
    } else if (blockIdx.x < cvtB + wB) {
        int i = (blockIdx.x - cvtB) * 256 + tid;
        if (i < 128 * 256) {  // W1: MT=256, NCT=16
            int j = i & 7, L = (i >> 3) & 63, c = (i >> 9) & 15, kk = i >> 13;
            int k = kk * 32 + (L >> 4) * 8 + j;
            int col = c * 16 + (L & 15);
            float v = (col < 128) ? Ws1[k * 128 + col] : Wn1[k * 128 + (col - 128)];
            W1f[i] = f2bf(v);
        } else {
            int idx = i - 128 * 256;
            if (idx < 128 * 128) {  // W2: MT=128, NCT=8
                int j = idx & 7, L = (idx >> 3) & 63, c = (idx >> 9) & 7, kk = idx >> 12;
                int k = kk * 32 + (L >> 4) * 8 + j;
                int col = c * 16 + (L & 15);
                float v = (col < 64) ? Ws2[k * 64 + col] : Wn2[k * 64 + (col - 64)];
                W2f[idx] = f2bf(v);
            }
        }
    } else {
        __shared__ int hist[512];
        int blk = blockIdx.x - cvtB - wB;
        int e0 = blk * P_EPB, e1 = min(e0 + P_EPB, E);
        for (int b = tid; b < 512; b += 256) hist[b] = 0;
        __syncthreads();
        for (int e = e0 + tid; e < e1; e += 256) atomicAdd(&hist[dst[e] >> BINSHIFT], 1);
        __syncthreads();
        for (int b = tid; b < NB; b += 256) counts[blk * NB + b] = hist[b];
    }
}

// ------------------------------------------------ p2a: per-bin scan over edge-blocks
__global__ __launch_bounds__(256) void p2a(const int* __restrict__ counts,
                                           int* __restrict__ segrel,
                                           int* __restrict__ tot, int NB, int NBLK) {
    __shared__ int s[256];
    int b = blockIdx.x, t = threadIdx.x;
    int v = (t < NBLK) ? counts[t * NB + b] : 0;
    s[t] = v;
    __syncthreads();
    scan256(s, t);
    if (t < NBLK) segrel[t * NB + b] = s[t] - v;
    if (t == 255) tot[b] = s[255];
}

// ------------------------------------------------ p2b: bin bases
__global__ __launch_bounds__(256) void p2b(const int* __restrict__ tot,
                                           int* __restrict__ binBase, int NB, int E) {
    __shared__ int s[256];
    int t = threadIdx.x;
    int v = (t < NB) ? tot[t] : 0;
    s[t] = v;
    __syncthreads();
    scan256(s, t);
    if (t < NB) binBase[t] = s[t] - v;
    if (t == 0) binBase[NB] = E;
}

// ------------------------------------------------ p3: LDS-binned scatter of pairs
__global__ __launch_bounds__(512) void p3_scatter(const int* __restrict__ src,
                                                  const int* __restrict__ dst,
                                                  const int* __restrict__ segrel,
                                                  const int* __restrict__ binBase,
                                                  uint2* __restrict__ pairs, int E, int NB) {
    __shared__ uint2 lp[P_EPB];
    __shared__ int hist[512];
    __shared__ int sBase[513];
    __shared__ int cursor[512];
    int t = threadIdx.x;
    int blk = blockIdx.x;
    int e0 = blk * P_EPB, e1 = min(e0 + P_EPB, E), m = e1 - e0;
    hist[t] = 0;
    __syncthreads();
    for (int e = e0 + t; e < e1; e += 512) atomicAdd(&hist[dst[e] >> BINSHIFT], 1);
    __syncthreads();
    int h = hist[t];
    scan512(hist, t);
    int excl = hist[t] - h;
    sBase[t] = excl;
    cursor[t] = excl;
    if (t == 0) sBase[512] = m;
    __syncthreads();
    for (int e = e0 + t; e < e1; e += 512) {
        int d = dst[e];
        int pos = atomicAdd(&cursor[d >> BINSHIFT], 1);
        lp[pos] = make_uint2((unsigned)src[e], (unsigned)d);
    }
    __syncthreads();
    for (int i = t; i < m; i += 512) {
        int lo = 0, hi = NB;
        while (hi - lo > 1) {
            int mid = (lo + hi) >> 1;
            if (sBase[mid] <= i) lo = mid; else hi = mid;
        }
        pairs[binBase[lo] + segrel[blk * NB + lo] + (i - sBase[lo])] = lp[i];
    }
}

// ------------------------------------------------ p4: per-bin CSR finalize
__global__ __launch_bounds__(512) void p4_csr(const uint2* __restrict__ pairs,
                                              const int* __restrict__ binBase,
                                              int* __restrict__ row_start,
                                              int* __restrict__ cntg,
                                              float* __restrict__ inv_deg,
                                              int* __restrict__ csr_src, int N) {
    __shared__ int ncnt[512];
    __shared__ int cursor[512];
    __shared__ int lsrc[LDS_CAP];
    int t = threadIdx.x;
    int b = blockIdx.x;
    int e0 = binBase[b], e1 = binBase[b + 1], m = e1 - e0;
    int nbase = b << BINSHIFT;
    int nn = min(N - nbase, BINW);
    ncnt[t] = 0;
    __syncthreads();
    for (int i = e0 + t; i < e1; i += 512) atomicAdd(&ncnt[pairs[i].y - nbase], 1);
    __syncthreads();
    int c = ncnt[t];
    scan512(ncnt, t);
    int excl = ncnt[t] - c;
    if (t < nn) {
        int node = nbase + t;
        row_start[node] = e0 + excl;
        cntg[node] = c;
        inv_deg[node] = 1.0f / fmaxf((float)c, 1.0f);
    }
    cursor[t] = excl;
    __syncthreads();
    for (int i = e0 + t; i < e1; i += 512) {
        uint2 p = pairs[i];
        int pos = atomicAdd(&cursor[p.y - nbase], 1);
        if (pos < LDS_CAP) lsrc[pos] = (int)p.x;
    }
    __syncthreads();
    int mm = min(m, LDS_CAP);
    for (int i = t; i < mm; i += 512) csr_src[e0 + i] = lsrc[i];
}

// ---------------------------------------------------------------- dual GEMM (MFMA bf16)
// Y = A[N,128] @ Wcat[128,MT].
//  cols [0,MSELF)  -> self output: bf16 (SELFBF) or fp32, row-major
//  cols [MSELF,MT) -> bf16 row-major Ynb[node][MT-MSELF]  (full-width gather rows)
// FUSEBN: A = BN+ReLU applied on-the-fly per input column from sums/gamma/beta.
template <int MT, int MSELF, bool SELFBF, bool FUSEBN>
__global__ __launch_bounds__(256) void gemm_dual(const unsigned short* __restrict__ A,
                                                 const unsigned short* __restrict__ Wf,
                                                 float* __restrict__ YselfF,
                                                 unsigned short* __restrict__ YselfB,
                                                 unsigned short* __restrict__ Ynb, int N,
                                                 const float* __restrict__ sums,
                                                 const float* __restrict__ gamma,
                                                 const float* __restrict__ beta,
                                                 float invN) {
    constexpr int K = 128;
    constexpr int NCT = MT / 16;
    constexpr int KS = K / 32;
    constexpr int MNB = MT - MSELF;
    __shared__ unsigned short Bl[KS * NCT * 64 * 8];
    __shared__ float ssc[128], ssh[128];

    for (int i = threadIdx.x; i < KS * NCT * 64; i += 256)
        ((short8*)Bl)[i] = ((const short8*)Wf)[i];
    if (FUSEBN && threadIdx.x < 128) {
        int c = threadIdx.x;
        float mu = sums[c] * invN;
        float var = sums[128 + c] * invN - mu * mu;
        float sc = gamma[c] * rsqrtf(var + EPS_BN);
        ssc[c] = sc;
        ssh[c] = beta[c] - mu * sc;
    }
    __syncthreads();

    int wv = threadIdx.x >> 6, lane = threadIdx.x & 63;
    int row0 = blockIdx.x * 128 + wv * 32;
    int m = lane & 15, quad = lane >> 4;

    short8 afrag[2][KS];
#pragma unroll
    for (int t = 0; t < 2; t++) {
        int arow = row0 + t * 16 + m;
        if (arow >= N) arow = N - 1;
        const unsigned short* aptr = A + (size_t)arow * K + quad * 8;
#pragma unroll
        for (int kk = 0; kk < KS; kk++) {
            short8 raw = *(const short8*)(aptr + kk * 32);
            if (FUSEBN) {
#pragma unroll
                for (int j = 0; j < 8; j++) {
                    int c = kk * 32 + quad * 8 + j;
                    float f = bf2f((unsigned short)raw[j]) * ssc[c] + ssh[c];
                    raw[j] = (short)f2bf(fmaxf(f, 0.f));
                }
            }
            afrag[t][kk] = raw;
        }
    }

    f32x4 acc[2][NCT];
#pragma unroll
    for (int t = 0; t < 2; t++)
        for (int c = 0; c < NCT; c++)
            for (int j = 0; j < 4; j++) acc[t][c][j] = 0.f;

#pragma unroll
    for (int kk = 0; kk < KS; kk++) {
#pragma unroll
        for (int c = 0; c < NCT; c++) {
            short8 bfrag = *(const short8*)&Bl[((kk * NCT + c) * 64 + lane) * 8];
#pragma unroll
            for (int t = 0; t < 2; t++)
                acc[t][c] = __builtin_amdgcn_mfma_f32_16x16x32_bf16(afrag[t][kk], bfrag,
                                                                    acc[t][c], 0, 0, 0);
        }
    }

    // C/D layout: col = lane&15, row = quad*4 + reg
#pragma unroll
    for (int t = 0; t < 2; t++) {
#pragma unroll
        for (int c = 0; c < NCT; c++) {
            int colg = c * 16 + m;
#pragma unroll
            for (int r = 0; r < 4; r++) {
                int row = row0 + t * 16 + quad * 4 + r;
                if (row < N) {
                    float v = acc[t][c][r];
                    if (colg < MSELF) {
                        if (SELFBF)
                            YselfB[(size_t)row * MSELF + colg] = f2bf(v);
                        else
                            YselfF[(size_t)row * MSELF + colg] = v;
                    } else {
                        Ynb[(size_t)row * MNB + (colg - MSELF)] = f2bf(v);
                    }
                }
            }
        }
    }
}

// ------------------------------------------------- aggregation, full-row broadcast
// Layer 1: one wave per node; 64 lanes x uint = full 256B table row per edge;
// 8-edge unroll -> 2KB in flight per wave. Self bf16 in, h1 bf16 out.
__global__ __launch_bounds__(256) void agg_row128(const unsigned int* __restrict__ Sb,
                                                  const unsigned int* __restrict__ T,
                                                  const int* __restrict__ row_start,
                                                  const int* __restrict__ cnt,
                                                  const float* __restrict__ inv_deg,
                                                  const int* __restrict__ csr_src,
                                                  const float* __restrict__ bias,
                                                  unsigned int* __restrict__ Out, int N) {
    int wv = threadIdx.x >> 6, lane = threadIdx.x & 63;
    int n = blockIdx.x * 4 + wv;
    if (n >= N) return;
    int start = row_start[n];
    int ec = cnt[n];
    float inv = inv_deg[n];
    float a0 = 0.f, a1 = 0.f;
    int e = 0;
    for (; e + 7 < ec; e += 8) {
        int i0 = csr_src[start + e];
        int i1 = csr_src[start + e + 1];
        int i2 = csr_src[start + e + 2];
        int i3 = csr_src[start + e + 3];
        int i4 = csr_src[start + e + 4];
        int i5 = csr_src[start + e + 5];
        int i6 = csr_src[start + e + 6];
        int i7 = csr_src[start + e + 7];
        unsigned u0 = T[(size_t)i0 * 64 + lane];
        unsigned u1 = T[(size_t)i1 * 64 + lane];
        unsigned u2 = T[(size_t)i2 * 64 + lane];
        unsigned u3 = T[(size_t)i3 * 64 + lane];
        unsigned u4 = T[(size_t)i4 * 64 + lane];
        unsigned u5 = T[(size_t)i5 * 64 + lane];
        unsigned u6 = T[(size_t)i6 * 64 + lane];
        unsigned u7 = T[(size_t)i7 * 64 + lane];
        a0 += bflo(u0) + bflo(u1) + bflo(u2) + bflo(u3) +
              bflo(u4) + bflo(u5) + bflo(u6) + bflo(u7);
        a1 += bfhi(u0) + bfhi(u1) + bfhi(u2) + bfhi(u3) +
              bfhi(u4) + bfhi(u5) + bfhi(u6) + bfhi(u7);
    }
    for (; e < ec; e++) {
        unsigned u0 = T[(size_t)csr_src[start + e] * 64 + lane];
        a0 += bflo(u0);
        a1 += bfhi(u0);
    }
    unsigned su = Sb[(size_t)n * 64 + lane];
    int c = lane * 2;
    float h0 = bflo(su) + a0 * inv + bias[c];
    float h1 = bfhi(su) + a1 * inv + bias[c + 1];
    Out[(size_t)n * 64 + lane] = (unsigned)f2bf(h0) | ((unsigned)f2bf(h1) << 16);
}

// Layer 2: two 32-lane groups per wave (one node each); uint/lane = full 128B row
// per edge; 4-edge unroll -> 2 x 4 x 128B = 1KB in flight. Self fp32 in d_out,
// out fp32 in-place (group reads its own row before writing it).
__global__ __launch_bounds__(256) void agg_row64(const unsigned int* __restrict__ T,
                                                 const int* __restrict__ row_start,
                                                 const int* __restrict__ cnt,
                                                 const float* __restrict__ inv_deg,
                                                 const int* __restrict__ csr_src,
                                                 const float* __restrict__ bias,
                                                 float* Self, int N) {
    int wv = threadIdx.x >> 6, L = threadIdx.x & 63;
    int g = L >> 5, h = L & 31;
    int n = (blockIdx.x * 4 + wv) * 2 + g;
    if (n >= N) return;
    int start = row_start[n];
    int ec = cnt[n];
    float inv = inv_deg[n];
    float a0 = 0.f, a1 = 0.f;
    int e = 0;
    for (; e + 3 < ec; e += 4) {
        int i0 = csr_src[start + e];
        int i1 = csr_src[start + e + 1];
        int i2 = csr_src[start + e + 2];
        int i3 = csr_src[start + e + 3];
        unsigned u0 = T[(size_t)i0 * 32 + h];
        unsigned u1 = T[(size_t)i1 * 32 + h];
        unsigned u2 = T[(size_t)i2 * 32 + h];
        unsigned u3 = T[(size_t)i3 * 32 + h];
        a0 += bflo(u0) + bflo(u1) + bflo(u2) + bflo(u3);
        a1 += bfhi(u0) + bfhi(u1) + bfhi(u2) + bfhi(u3);
    }
    for (; e < ec; e++) {
        unsigned u0 = T[(size_t)csr_src[start + e] * 32 + h];
        a0 += bflo(u0);
        a1 += bfhi(u0);
    }
    int c = h * 2;
    size_t off = (size_t)n * 64 + c;
    float s0 = Self[off], s1 = Self[off + 1];
    Self[off] = s0 + a0 * inv + bias[c];
    Self[off + 1] = s1 + a1 * inv + bias[c + 1];
}

// ---------------------------------------------------------------- BatchNorm stats
// bf16 input, M=128: thread handles 8 consecutive cols (uint4 = 8 bf16)
__global__ __launch_bounds__(256) void bn_stats_bf128(const unsigned short* __restrict__ H,
                                                      float* __restrict__ sums, int N) {
    int tid = threadIdx.x;
    float s[8] = {0, 0, 0, 0, 0, 0, 0, 0}, q[8] = {0, 0, 0, 0, 0, 0, 0, 0};
    const uint4* H8 = (const uint4*)H;
    int total8 = N * 16;
    for (int i = blockIdx.x * 256 + tid; i < total8; i += 256 * gridDim.x) {
        uint4 v = H8[i];
        unsigned w[4] = {v.x, v.y, v.z, v.w};
#pragma unroll
        for (int j = 0; j < 4; j++) {
            float f0 = bflo(w[j]), f1 = bfhi(w[j]);
            s[2 * j] += f0; q[2 * j] += f0 * f0;
            s[2 * j + 1] += f1; q[2 * j + 1] += f1 * f1;
        }
    }
    __shared__ float red[256 * 16];
    for (int j = 0; j < 8; j++) {
        red[tid * 16 + j] = s[j];
        red[tid * 16 + 8 + j] = q[j];
    }
    __syncthreads();
    if (tid < 16) {
        float rs[16];
        for (int j = 0; j < 16; j++) rs[j] = 0.f;
        for (int p = tid; p < 256; p += 16)
            for (int j = 0; j < 16; j++) rs[j] += red[p * 16 + j];
        int cc = tid * 8;
        for (int j = 0; j < 8; j++) {
            atomicAdd(&sums[cc + j], rs[j]);
            atomicAdd(&sums[128 + cc + j], rs[8 + j]);
        }
    }
}

// fp32 input (layer-2 output in d_out)
template <int M>
__global__ __launch_bounds__(256) void bn_stats(const float* __restrict__ H,
                                                float* __restrict__ sums, int N) {
    int tid = threadIdx.x;
    int c0 = (tid * 4) % M;
    float s[4] = {0.f, 0.f, 0.f, 0.f}, q[4] = {0.f, 0.f, 0.f, 0.f};
    const float4* H4 = (const float4*)H;
    int total4 = N * (M / 4);
    for (int i = blockIdx.x * 256 + tid; i < total4; i += 256 * gridDim.x) {
        float4 v = H4[i];
        s[0] += v.x; q[0] += v.x * v.x;
        s[1] += v.y; q[1] += v.y * v.y;
        s[2] += v.z; q[2] += v.z * v.z;
        s[3] += v.w; q[3] += v.w * v.w;
    }
    __shared__ float red[256 * 8];
    for (int j = 0; j < 4; j++) {
        red[tid * 8 + j] = s[j];
        red[tid * 8 + 4 + j] = q[j];
    }
    __syncthreads();
    constexpr int GRP = M / 4;
    if (tid < GRP) {
        float rs[8] = {0.f, 0.f, 0.f, 0.f, 0.f, 0.f, 0.f, 0.f};
        for (int p = tid; p < 256; p += GRP)
            for (int j = 0; j < 8; j++) rs[j] += red[p * 8 + j];
        for (int j = 0; j < 4; j++) {
            atomicAdd(&sums[c0 + j], rs[j]);
            atomicAdd(&sums[M + c0 + j], rs[4 + j]);
        }
    }
}

// layer-2 apply (finalize folded): fp32 in-place, no ReLU
__global__ __launch_bounds__(256) void bn_apply_f64(float* H, const float* __restrict__ sums,
                                                    const float* __restrict__ gamma,
                                                    const float* __restrict__ beta,
                                                    int N, float invN) {
    __shared__ float ss[128];
    int tid = threadIdx.x;
    if (tid < 64) {
        float mu = sums[tid] * invN;
        float var = sums[64 + tid] * invN - mu * mu;
        float sc = gamma[tid] * rsqrtf(var + EPS_BN);
        ss[tid] = sc;
        ss[64 + tid] = beta[tid] - mu * sc;
    }
    __syncthreads();
    int total4 = N * 16;
    float4* H4 = (float4*)H;
    for (int i = blockIdx.x * 256 + threadIdx.x; i < total4; i += 256 * gridDim.x) {
        int c0 = (i * 4) & 63;
        float4 v = H4[i];
        float4 sc = *(const float4*)&ss[c0];
        float4 sh = *(const float4*)&ss[64 + c0];
        v.x = v.x * sc.x + sh.x;
        v.y = v.y * sc.y + sh.y;
        v.z = v.z * sc.z + sh.z;
        v.w = v.w * sc.w + sh.w;
        H4[i] = v;
    }
}

// ---------------------------------------------------------------- launch
extern "C" void kernel_launch(void* const* d_in, const int* in_sizes, int n_in,
                              void* d_out, int out_size, void* d_ws, size_t ws_size,
                              hipStream_t stream) {
    const float* X = (const float*)d_in[0];
    const int* src = (const int*)d_in[1];
    const int* dst = (const int*)d_in[2];
    const float* Wself1 = (const float*)d_in[3];
    const float* Wneigh1 = (const float*)d_in[4];
    const float* b1 = (const float*)d_in[5];
    const float* g1 = (const float*)d_in[6];
    const float* be1 = (const float*)d_in[7];
    const float* Wself2 = (const float*)d_in[8];
    const float* Wneigh2 = (const float*)d_in[9];
    const float* b2 = (const float*)d_in[10];
    const float* g2 = (const float*)d_in[11];
    const float* be2 = (const float*)d_in[12];
    float* out = (float*)d_out;

    const int N = in_sizes[0] / 128;
    const int E = in_sizes[1];
    const int NB = (N + BINW - 1) >> BINSHIFT;    // 196
    const int NBLK = (E + P_EPB - 1) / P_EPB;     // 196 (<=256 required by p2a)

    char* p = (char*)d_ws;
    auto carve = [&](size_t bytes) {
        char* r = p;
        p += (bytes + 255) & ~(size_t)255;
        return r;
    };
    float* sums1 = (float*)carve(256 * 4);
    float* sums2 = (float*)carve(128 * 4);
    size_t zero_bytes = (size_t)(p - (char*)d_ws);
    int* counts = (int*)carve((size_t)NBLK * NB * 4);
    int* segrel = (int*)carve((size_t)NBLK * NB * 4);
    int* tot = (int*)carve((size_t)NB * 4);
    int* binBase = (int*)carve((size_t)(NB + 1) * 4);
    uint2* pairs = (uint2*)carve((size_t)E * 8);
    int* csr_src = (int*)carve((size_t)E * 4);
    int* row_start = (int*)carve((size_t)N * 4);
    int* cntg = (int*)carve((size_t)N * 4);
    float* inv_deg = (float*)carve((size_t)N * 4);
    unsigned short* W1f = (unsigned short*)carve(128 * 256 * 2);
    unsigned short* W2f = (unsigned short*)carve(128 * 128 * 2);
    unsigned short* Xb = (unsigned short*)carve((size_t)N * 128 * 2);
    unsigned short* bufS = (unsigned short*)carve((size_t)N * 128 * 2);  // self1 bf16
    unsigned short* tab = (unsigned short*)carve((size_t)N * 128 * 2);   // row-major
    unsigned short* h1b = (unsigned short*)carve((size_t)N * 128 * 2);   // h1 pre-BN bf16

    hipMemsetAsync(d_ws, 0, zero_bytes, stream);

    const int cvtB = 1024, wB = 192;
    const float invN = 1.0f / (float)N;
    prep_kernel<<<cvtB + wB + NBLK, 256, 0, stream>>>(X, Xb, N * 32, Wself1, Wneigh1,
                                                      Wself2, Wneigh2, W1f, W2f, dst,
                                                      counts, E, NB, cvtB, wB);
    p2a<<<NB, 256, 0, stream>>>(counts, segrel, tot, NB, NBLK);
    p2b<<<1, 256, 0, stream>>>(tot, binBase, NB, E);
    p3_scatter<<<NBLK, 512, 0, stream>>>(src, dst, segrel, binBase, pairs, E, NB);
    p4_csr<<<NB, 512, 0, stream>>>(pairs, binBase, row_start, cntg, inv_deg, csr_src, N);

    int ggrid = (N + 127) / 128;
    // ---- layer 1 (128 -> 128): self bf16 -> bufS, neigh bf16 row-major -> tab
    gemm_dual<256, 128, true, false><<<ggrid, 256, 0, stream>>>(
        Xb, W1f, nullptr, bufS, tab, N, nullptr, nullptr, nullptr, 0.f);
    agg_row128<<<(N + 3) / 4, 256, 0, stream>>>(
        (const unsigned int*)bufS, (const unsigned int*)tab, row_start, cntg, inv_deg,
        csr_src, b1, (unsigned int*)h1b, N);
    bn_stats_bf128<<<256, 256, 0, stream>>>(h1b, sums1, N);

    // ---- layer 2 (128 -> 64): BN1+ReLU fused into A-load; self fp32 -> out
    gemm_dual<128, 64, false, true><<<ggrid, 256, 0, stream>>>(
        h1b, W2f, out, nullptr, tab, N, sums1, g1, be1, invN);
    agg_row64<<<(N + 7) / 8, 256, 0, stream>>>(
        (const unsigned int*)tab, row_start, cntg, inv_deg, csr_src, b2, out, N);
    bn_stats<64><<<256, 256, 0, stream>>>(out, sums2, N);
    bn_apply_f64<<<2048, 256, 0, stream>>>(out, sums2, g2, be2, N, invN);
}

// Round 8
// 425.289 us; speedup vs baseline: 2.1163x; 1.0243x over previous
//
#include <hip/hip_runtime.h>

#define EPS_BN 1e-5f
#define BINSHIFT 9
#define BINW 512
#define P_EPB 8192   // edges per block in count/scatter passes
#define LDS_CAP 10240

typedef __attribute__((ext_vector_type(8))) short short8;
typedef __attribute__((ext_vector_type(4))) float f32x4;

__device__ __forceinline__ unsigned short f2bf(float x) {
    unsigned int u = __float_as_uint(x);
    u += 0x7fffu + ((u >> 16) & 1u);
    return (unsigned short)(u >> 16);
}
__device__ __forceinline__ float bf2f(unsigned short h) {
    return __uint_as_float(((unsigned int)h) << 16);
}
__device__ __forceinline__ float bflo(unsigned u) { return __uint_as_float(u << 16); }
__device__ __forceinline__ float bfhi(unsigned u) { return __uint_as_float(u & 0xffff0000u); }

// inclusive scans (all threads of the block must enter)
__device__ __forceinline__ void scan512(int* a, int t) {
    for (int off = 1; off < 512; off <<= 1) {
        int v = (t >= off) ? a[t - off] : 0;
        __syncthreads();
        a[t] += v;
        __syncthreads();
    }
}
__device__ __forceinline__ void scan256(int* a, int t) {
    for (int off = 1; off < 256; off <<= 1) {
        int v = (t >= off) ? a[t - off] : 0;
        __syncthreads();
        a[t] += v;
        __syncthreads();
    }
}

// ------------------------------------------------ prep: cvt_w | p1_count
__global__ __launch_bounds__(256) void prep_kernel(
    const float* __restrict__ Ws1, const float* __restrict__ Wn1,
    const float* __restrict__ Ws2, const float* __restrict__ Wn2,
    unsigned short* __restrict__ W1f, unsigned short* __restrict__ W2f,
    const int* __restrict__ dst, int* __restrict__ counts, int E, int NB, int wB) {
    int tid = threadIdx.x;
    if (blockIdx.x < wB) {
        int i = blockIdx.x * 256 + tid;
        if (i < 128 * 256) {  // W1: MT=256, NCT=16
            int j = i & 7, L = (i >> 3) & 63, c = (i >> 9) & 15, kk = i >> 13;
            int k = kk * 32 + (L >> 4) * 8 + j;
            int col = c * 16 + (L & 15);
            float v = (col < 128) ? Ws1[k * 128 + col] : Wn1[k * 128 + (col - 128)];
            W1f[i] = f2bf(v);
        } else {
            int idx = i - 128 * 256;
            if (idx < 128 * 128) {  // W2: MT=128, NCT=8
                int j = idx & 7, L = (idx >> 3) & 63, c = (idx >> 9) & 7, kk = idx >> 12;
                int k = kk * 32 + (L >> 4) * 8 + j;
                int col = c * 16 + (L & 15);
                float v = (col < 64) ? Ws2[k * 64 + col] : Wn2[k * 64 + (col - 64)];
                W2f[idx] = f2bf(v);
            }
        }
    } else {
        __shared__ int hist[512];
        int blk = blockIdx.x - wB;
        int e0 = blk * P_EPB, e1 = min(e0 + P_EPB, E);
        for (int b = tid; b < 512; b += 256) hist[b] = 0;
        __syncthreads();
        for (int e = e0 + tid; e < e1; e += 256) atomicAdd(&hist[dst[e] >> BINSHIFT], 1);
        __syncthreads();
        for (int b = tid; b < NB; b += 256) counts[blk * NB + b] = hist[b];
    }
}

// ------------------------------------------------ p2a: per-bin scan over edge-blocks
__global__ __launch_bounds__(256) void p2a(const int* __restrict__ counts,
                                           int* __restrict__ segrel,
                                           int* __restrict__ tot, int NB, int NBLK) {
    __shared__ int s[256];
    int b = blockIdx.x, t = threadIdx.x;
    int v = (t < NBLK) ? counts[t * NB + b] : 0;
    s[t] = v;
    __syncthreads();
    scan256(s, t);
    if (t < NBLK) segrel[t * NB + b] = s[t] - v;
    if (t == 255) tot[b] = s[255];
}

// ------------------------------------------------ p3: LDS-binned scatter of pairs
// (binBase recomputed in-block from tot: 512-wide LDS scan)
__global__ __launch_bounds__(512) void p3_scatter(const int* __restrict__ src,
                                                  const int* __restrict__ dst,
                                                  const int* __restrict__ segrel,
                                                  const int* __restrict__ tot,
                                                  uint2* __restrict__ pairs, int E, int NB) {
    __shared__ uint2 lp[P_EPB];
    __shared__ int hist[512];
    __shared__ int sBase[513];
    __shared__ int cursor[512];
    __shared__ int bbase[512];
    int t = threadIdx.x;
    int blk = blockIdx.x;
    int e0 = blk * P_EPB, e1 = min(e0 + P_EPB, E), m = e1 - e0;
    int tv = (t < NB) ? tot[t] : 0;
    bbase[t] = tv;
    __syncthreads();
    scan512(bbase, t);
    bbase[t] -= tv;  // exclusive bin base
    hist[t] = 0;
    __syncthreads();
    for (int e = e0 + t; e < e1; e += 512) atomicAdd(&hist[dst[e] >> BINSHIFT], 1);
    __syncthreads();
    int h = hist[t];
    scan512(hist, t);
    int excl = hist[t] - h;
    sBase[t] = excl;
    cursor[t] = excl;
    if (t == 0) sBase[512] = m;
    __syncthreads();
    for (int e = e0 + t; e < e1; e += 512) {
        int d = dst[e];
        int pos = atomicAdd(&cursor[d >> BINSHIFT], 1);
        lp[pos] = make_uint2((unsigned)src[e], (unsigned)d);
    }
    __syncthreads();
    for (int i = t; i < m; i += 512) {
        int lo = 0, hi = NB;
        while (hi - lo > 1) {
            int mid = (lo + hi) >> 1;
            if (sBase[mid] <= i) lo = mid; else hi = mid;
        }
        pairs[bbase[lo] + segrel[blk * NB + lo] + (i - sBase[lo])] = lp[i];
    }
}

// ------------------------------------------------ p4: per-bin CSR finalize
__global__ __launch_bounds__(512) void p4_csr(const uint2* __restrict__ pairs,
                                              const int* __restrict__ tot,
                                              int* __restrict__ row_start,
                                              int* __restrict__ cntg,
                                              float* __restrict__ inv_deg,
                                              int* __restrict__ csr_src, int N, int NB) {
    __shared__ int ncnt[512];
    __shared__ int cursor[512];
    __shared__ int bb[512];
    __shared__ int lsrc[LDS_CAP];
    int t = threadIdx.x;
    int b = blockIdx.x;
    int tv = (t < NB) ? tot[t] : 0;
    bb[t] = tv;
    __syncthreads();
    scan512(bb, t);
    int e1 = bb[b];           // inclusive: end of bin b
    int e0 = bb[b] - tot[b];  // exclusive: start of bin b
    int m = e1 - e0;
    int nbase = b << BINSHIFT;
    int nn = min(N - nbase, BINW);
    ncnt[t] = 0;
    __syncthreads();
    for (int i = e0 + t; i < e1; i += 512) atomicAdd(&ncnt[pairs[i].y - nbase], 1);
    __syncthreads();
    int c = ncnt[t];
    scan512(ncnt, t);
    int excl = ncnt[t] - c;
    if (t < nn) {
        int node = nbase + t;
        row_start[node] = e0 + excl;
        cntg[node] = c;
        inv_deg[node] = 1.0f / fmaxf((float)c, 1.0f);
    }
    cursor[t] = excl;
    __syncthreads();
    for (int i = e0 + t; i < e1; i += 512) {
        uint2 p = pairs[i];
        int pos = atomicAdd(&cursor[p.y - nbase], 1);
        if (pos < LDS_CAP) lsrc[pos] = (int)p.x;
    }
    __syncthreads();
    int mm = min(m, LDS_CAP);
    for (int i = t; i < mm; i += 512) csr_src[e0 + i] = lsrc[i];
}

// ---------------------------------------------------------------- dual GEMM (MFMA bf16)
// Y = A[N,128] @ Wcat[128,MT].  A is bf16 (Ab) or fp32 (Af, AFP32: inline cvt).
//  cols [0,MSELF)  -> self output: bf16 (SELFBF) or fp32, row-major
//  cols [MSELF,MT) -> bf16 row-major Ynb (full-width gather rows)
// FUSEBN: A = BN+ReLU applied on-the-fly per input column from sums/gamma/beta.
template <int MT, int MSELF, bool SELFBF, bool FUSEBN, bool AFP32>
__global__ __launch_bounds__(256) void gemm_dual(const unsigned short* __restrict__ Ab,
                                                 const float* __restrict__ Af,
                                                 const unsigned short* __restrict__ Wf,
                                                 float* __restrict__ YselfF,
                                                 unsigned short* __restrict__ YselfB,
                                                 unsigned short* __restrict__ Ynb, int N,
                                                 const float* __restrict__ sums,
                                                 const float* __restrict__ gamma,
                                                 const float* __restrict__ beta,
                                                 float invN) {
    constexpr int K = 128;
    constexpr int NCT = MT / 16;
    constexpr int KS = K / 32;
    constexpr int MNB = MT - MSELF;
    __shared__ unsigned short Bl[KS * NCT * 64 * 8];
    __shared__ float ssc[128], ssh[128];

    for (int i = threadIdx.x; i < KS * NCT * 64; i += 256)
        ((short8*)Bl)[i] = ((const short8*)Wf)[i];
    if (FUSEBN && threadIdx.x < 128) {
        int c = threadIdx.x;
        float mu = sums[c] * invN;
        float var = sums[128 + c] * invN - mu * mu;
        float sc = gamma[c] * rsqrtf(var + EPS_BN);
        ssc[c] = sc;
        ssh[c] = beta[c] - mu * sc;
    }
    __syncthreads();

    int wv = threadIdx.x >> 6, lane = threadIdx.x & 63;
    int row0 = blockIdx.x * 128 + wv * 32;
    int m = lane & 15, quad = lane >> 4;

    short8 afrag[2][KS];
#pragma unroll
    for (int t = 0; t < 2; t++) {
        int arow = row0 + t * 16 + m;
        if (arow >= N) arow = N - 1;
#pragma unroll
        for (int kk = 0; kk < KS; kk++) {
            short8 raw;
            if (AFP32) {
                const float* ap = Af + (size_t)arow * K + quad * 8 + kk * 32;
                f32x4 a = *(const f32x4*)ap;
                f32x4 b = *(const f32x4*)(ap + 4);
#pragma unroll
                for (int j = 0; j < 4; j++) {
                    raw[j] = (short)f2bf(a[j]);
                    raw[4 + j] = (short)f2bf(b[j]);
                }
            } else {
                raw = *(const short8*)(Ab + (size_t)arow * K + quad * 8 + kk * 32);
            }
            if (FUSEBN) {
#pragma unroll
                for (int j = 0; j < 8; j++) {
                    int c = kk * 32 + quad * 8 + j;
                    float f = bf2f((unsigned short)raw[j]) * ssc[c] + ssh[c];
                    raw[j] = (short)f2bf(fmaxf(f, 0.f));
                }
            }
            afrag[t][kk] = raw;
        }
    }

    f32x4 acc[2][NCT];
#pragma unroll
    for (int t = 0; t < 2; t++)
        for (int c = 0; c < NCT; c++)
            for (int j = 0; j < 4; j++) acc[t][c][j] = 0.f;

#pragma unroll
    for (int kk = 0; kk < KS; kk++) {
#pragma unroll
        for (int c = 0; c < NCT; c++) {
            short8 bfrag = *(const short8*)&Bl[((kk * NCT + c) * 64 + lane) * 8];
#pragma unroll
            for (int t = 0; t < 2; t++)
                acc[t][c] = __builtin_amdgcn_mfma_f32_16x16x32_bf16(afrag[t][kk], bfrag,
                                                                    acc[t][c], 0, 0, 0);
        }
    }

    // C/D layout: col = lane&15, row = quad*4 + reg
#pragma unroll
    for (int t = 0; t < 2; t++) {
#pragma unroll
        for (int c = 0; c < NCT; c++) {
            int colg = c * 16 + m;
#pragma unroll
            for (int r = 0; r < 4; r++) {
                int row = row0 + t * 16 + quad * 4 + r;
                if (row < N) {
                    float v = acc[t][c][r];
                    if (colg < MSELF) {
                        if (SELFBF)
                            YselfB[(size_t)row * MSELF + colg] = f2bf(v);
                        else
                            YselfF[(size_t)row * MSELF + colg] = v;
                    } else {
                        Ynb[(size_t)row * MNB + (colg - MSELF)] = f2bf(v);
                    }
                }
            }
        }
    }
}

// ------------------------------------------------- aggregation + fused BN stats
// Layer 1: one wave per node (persistent, stride totalWaves); 64 lanes x uint =
// full 256B table row per edge; 8-edge unroll. Self bf16 in, h1 bf16 out.
// Column sums/sumsqs accumulate in registers over the node loop -> LDS -> atomics.
__global__ __launch_bounds__(256) void agg_row128(const unsigned int* __restrict__ Sb,
                                                  const unsigned int* __restrict__ T,
                                                  const int* __restrict__ row_start,
                                                  const int* __restrict__ cnt,
                                                  const float* __restrict__ inv_deg,
                                                  const int* __restrict__ csr_src,
                                                  const float* __restrict__ bias,
                                                  unsigned int* __restrict__ Out,
                                                  float* __restrict__ sums,
                                                  int N, int totalWaves) {
    int wv = threadIdx.x >> 6, lane = threadIdx.x & 63;
    int c = lane * 2;
    float bs0 = bias[c], bs1 = bias[c + 1];
    float S0 = 0.f, S1 = 0.f, Q0 = 0.f, Q1 = 0.f;
    for (int n = blockIdx.x * 4 + wv; n < N; n += totalWaves) {
        int start = row_start[n];
        int ec = cnt[n];
        float inv = inv_deg[n];
        float a0 = 0.f, a1 = 0.f;
        int e = 0;
        for (; e + 7 < ec; e += 8) {
            int i0 = csr_src[start + e];
            int i1 = csr_src[start + e + 1];
            int i2 = csr_src[start + e + 2];
            int i3 = csr_src[start + e + 3];
            int i4 = csr_src[start + e + 4];
            int i5 = csr_src[start + e + 5];
            int i6 = csr_src[start + e + 6];
            int i7 = csr_src[start + e + 7];
            unsigned u0 = T[(size_t)i0 * 64 + lane];
            unsigned u1 = T[(size_t)i1 * 64 + lane];
            unsigned u2 = T[(size_t)i2 * 64 + lane];
            unsigned u3 = T[(size_t)i3 * 64 + lane];
            unsigned u4 = T[(size_t)i4 * 64 + lane];
            unsigned u5 = T[(size_t)i5 * 64 + lane];
            unsigned u6 = T[(size_t)i6 * 64 + lane];
            unsigned u7 = T[(size_t)i7 * 64 + lane];
            a0 += bflo(u0) + bflo(u1) + bflo(u2) + bflo(u3) +
                  bflo(u4) + bflo(u5) + bflo(u6) + bflo(u7);
            a1 += bfhi(u0) + bfhi(u1) + bfhi(u2) + bfhi(u3) +
                  bfhi(u4) + bfhi(u5) + bfhi(u6) + bfhi(u7);
        }
        for (; e < ec; e++) {
            unsigned u0 = T[(size_t)csr_src[start + e] * 64 + lane];
            a0 += bflo(u0);
            a1 += bfhi(u0);
        }
        unsigned su = Sb[(size_t)n * 64 + lane];
        float h0 = bflo(su) + a0 * inv + bs0;
        float h1 = bfhi(su) + a1 * inv + bs1;
        Out[(size_t)n * 64 + lane] = (unsigned)f2bf(h0) | ((unsigned)f2bf(h1) << 16);
        S0 += h0; Q0 += h0 * h0;
        S1 += h1; Q1 += h1 * h1;
    }
    __shared__ float ls[256];
    if (threadIdx.x < 256) ls[threadIdx.x] = 0.f;
    __syncthreads();
    atomicAdd(&ls[c], S0);
    atomicAdd(&ls[c + 1], S1);
    atomicAdd(&ls[128 + c], Q0);
    atomicAdd(&ls[129 + c], Q1);
    __syncthreads();
    if (threadIdx.x < 256) atomicAdd(&sums[threadIdx.x], ls[threadIdx.x]);
}

// Layer 2: two 32-lane groups per wave (one node each, persistent); uint/lane =
// full 128B row per edge; 4-edge unroll. Self fp32 in d_out, in-place update.
__global__ __launch_bounds__(256) void agg_row64(const unsigned int* __restrict__ T,
                                                 const int* __restrict__ row_start,
                                                 const int* __restrict__ cnt,
                                                 const float* __restrict__ inv_deg,
                                                 const int* __restrict__ csr_src,
                                                 const float* __restrict__ bias,
                                                 float* Self, float* __restrict__ sums,
                                                 int N, int totalHalf) {
    int wv = threadIdx.x >> 6, L = threadIdx.x & 63;
    int g = L >> 5, h = L & 31;
    int c = h * 2;
    float bs0 = bias[c], bs1 = bias[c + 1];
    float S0 = 0.f, S1 = 0.f, Q0 = 0.f, Q1 = 0.f;
    for (int n = (blockIdx.x * 4 + wv) * 2 + g; n < N; n += totalHalf) {
        int start = row_start[n];
        int ec = cnt[n];
        float inv = inv_deg[n];
        float a0 = 0.f, a1 = 0.f;
        int e = 0;
        for (; e + 3 < ec; e += 4) {
            int i0 = csr_src[start + e];
            int i1 = csr_src[start + e + 1];
            int i2 = csr_src[start + e + 2];
            int i3 = csr_src[start + e + 3];
            unsigned u0 = T[(size_t)i0 * 32 + h];
            unsigned u1 = T[(size_t)i1 * 32 + h];
            unsigned u2 = T[(size_t)i2 * 32 + h];
            unsigned u3 = T[(size_t)i3 * 32 + h];
            a0 += bflo(u0) + bflo(u1) + bflo(u2) + bflo(u3);
            a1 += bfhi(u0) + bfhi(u1) + bfhi(u2) + bfhi(u3);
        }
        for (; e < ec; e++) {
            unsigned u0 = T[(size_t)csr_src[start + e] * 32 + h];
            a0 += bflo(u0);
            a1 += bfhi(u0);
        }
        size_t off = (size_t)n * 64 + c;
        float h0 = Self[off] + a0 * inv + bs0;
        float h1 = Self[off + 1] + a1 * inv + bs1;
        Self[off] = h0;
        Self[off + 1] = h1;
        S0 += h0; Q0 += h0 * h0;
        S1 += h1; Q1 += h1 * h1;
    }
    __shared__ float ls[128];
    if (threadIdx.x < 128) ls[threadIdx.x] = 0.f;
    __syncthreads();
    atomicAdd(&ls[c], S0);
    atomicAdd(&ls[c + 1], S1);
    atomicAdd(&ls[64 + c], Q0);
    atomicAdd(&ls[65 + c], Q1);
    __syncthreads();
    if (threadIdx.x < 128) atomicAdd(&sums[threadIdx.x], ls[threadIdx.x]);
}

// layer-2 apply (finalize folded): fp32 in-place, no ReLU
__global__ __launch_bounds__(256) void bn_apply_f64(float* H, const float* __restrict__ sums,
                                                    const float* __restrict__ gamma,
                                                    const float* __restrict__ beta,
                                                    int N, float invN) {
    __shared__ float ss[128];
    int tid = threadIdx.x;
    if (tid < 64) {
        float mu = sums[tid] * invN;
        float var = sums[64 + tid] * invN - mu * mu;
        float sc = gamma[tid] * rsqrtf(var + EPS_BN);
        ss[tid] = sc;
        ss[64 + tid] = beta[tid] - mu * sc;
    }
    __syncthreads();
    int total4 = N * 16;
    float4* H4 = (float4*)H;
    for (int i = blockIdx.x * 256 + threadIdx.x; i < total4; i += 256 * gridDim.x) {
        int c0 = (i * 4) & 63;
        float4 v = H4[i];
        float4 sc = *(const float4*)&ss[c0];
        float4 sh = *(const float4*)&ss[64 + c0];
        v.x = v.x * sc.x + sh.x;
        v.y = v.y * sc.y + sh.y;
        v.z = v.z * sc.z + sh.z;
        v.w = v.w * sc.w + sh.w;
        H4[i] = v;
    }
}

// ---------------------------------------------------------------- launch
extern "C" void kernel_launch(void* const* d_in, const int* in_sizes, int n_in,
                              void* d_out, int out_size, void* d_ws, size_t ws_size,
                              hipStream_t stream) {
    const float* X = (const float*)d_in[0];
    const int* src = (const int*)d_in[1];
    const int* dst = (const int*)d_in[2];
    const float* Wself1 = (const float*)d_in[3];
    const float* Wneigh1 = (const float*)d_in[4];
    const float* b1 = (const float*)d_in[5];
    const float* g1 = (const float*)d_in[6];
    const float* be1 = (const float*)d_in[7];
    const float* Wself2 = (const float*)d_in[8];
    const float* Wneigh2 = (const float*)d_in[9];
    const float* b2 = (const float*)d_in[10];
    const float* g2 = (const float*)d_in[11];
    const float* be2 = (const float*)d_in[12];
    float* out = (float*)d_out;

    const int N = in_sizes[0] / 128;
    const int E = in_sizes[1];
    const int NB = (N + BINW - 1) >> BINSHIFT;    // 196
    const int NBLK = (E + P_EPB - 1) / P_EPB;     // 196 (<=256 required by p2a)

    char* p = (char*)d_ws;
    auto carve = [&](size_t bytes) {
        char* r = p;
        p += (bytes + 255) & ~(size_t)255;
        return r;
    };
    float* sums1 = (float*)carve(256 * 4);
    float* sums2 = (float*)carve(128 * 4);
    size_t zero_bytes = (size_t)(p - (char*)d_ws);
    int* counts = (int*)carve((size_t)NBLK * NB * 4);
    int* segrel = (int*)carve((size_t)NBLK * NB * 4);
    int* tot = (int*)carve((size_t)NB * 4);
    uint2* pairs = (uint2*)carve((size_t)E * 8);
    int* csr_src = (int*)carve((size_t)E * 4);
    int* row_start = (int*)carve((size_t)N * 4);
    int* cntg = (int*)carve((size_t)N * 4);
    float* inv_deg = (float*)carve((size_t)N * 4);
    unsigned short* W1f = (unsigned short*)carve(128 * 256 * 2);
    unsigned short* W2f = (unsigned short*)carve(128 * 128 * 2);
    unsigned short* bufS = (unsigned short*)carve((size_t)N * 128 * 2);  // self1 bf16
    unsigned short* tab = (unsigned short*)carve((size_t)N * 128 * 2);   // row-major
    unsigned short* h1b = (unsigned short*)carve((size_t)N * 128 * 2);   // h1 pre-BN bf16

    hipMemsetAsync(d_ws, 0, zero_bytes, stream);

    const int wB = 192;
    const float invN = 1.0f / (float)N;
    prep_kernel<<<wB + NBLK, 256, 0, stream>>>(Wself1, Wneigh1, Wself2, Wneigh2, W1f, W2f,
                                               dst, counts, E, NB, wB);
    p2a<<<NB, 256, 0, stream>>>(counts, segrel, tot, NB, NBLK);
    p3_scatter<<<NBLK, 512, 0, stream>>>(src, dst, segrel, tot, pairs, E, NB);
    p4_csr<<<NB, 512, 0, stream>>>(pairs, tot, row_start, cntg, inv_deg, csr_src, N, NB);

    int ggrid = (N + 127) / 128;
    // ---- layer 1 (128 -> 128): fp32 X in (inline cvt), self bf16, neigh bf16
    gemm_dual<256, 128, true, false, true><<<ggrid, 256, 0, stream>>>(
        nullptr, X, W1f, nullptr, bufS, tab, N, nullptr, nullptr, nullptr, 0.f);
    agg_row128<<<2048, 256, 0, stream>>>(
        (const unsigned int*)bufS, (const unsigned int*)tab, row_start, cntg, inv_deg,
        csr_src, b1, (unsigned int*)h1b, sums1, N, 8192);

    // ---- layer 2 (128 -> 64): BN1+ReLU fused into A-load; self fp32 -> out
    gemm_dual<128, 64, false, true, false><<<ggrid, 256, 0, stream>>>(
        h1b, nullptr, W2f, out, nullptr, tab, N, sums1, g1, be1, invN);
    agg_row64<<<2048, 256, 0, stream>>>(
        (const unsigned int*)tab, row_start, cntg, inv_deg, csr_src, b2, out, sums2,
        N, 16384);
    bn_apply_f64<<<2048, 256, 0, stream>>>(out, sums2, g2, be2, N, invN);
}

// Round 9
// 353.870 us; speedup vs baseline: 2.5434x; 1.2018x over previous
//
#include <hip/hip_runtime.h>

#define EPS_BN 1e-5f
#define BINSHIFT 9
#define BINW 512
#define P_EPB 8192   // edges per block in count/scatter passes
#define LDS_CAP 10240
#define NREP 32      // stat-accumulator replicas (atomic de-contention)

typedef __attribute__((ext_vector_type(8))) short short8;
typedef __attribute__((ext_vector_type(4))) float f32x4;

__device__ __forceinline__ unsigned short f2bf(float x) {
    unsigned int u = __float_as_uint(x);
    u += 0x7fffu + ((u >> 16) & 1u);
    return (unsigned short)(u >> 16);
}
__device__ __forceinline__ float bf2f(unsigned short h) {
    return __uint_as_float(((unsigned int)h) << 16);
}
__device__ __forceinline__ float bflo(unsigned u) { return __uint_as_float(u << 16); }
__device__ __forceinline__ float bfhi(unsigned u) { return __uint_as_float(u & 0xffff0000u); }

// inclusive scans (all threads of the block must enter)
__device__ __forceinline__ void scan512(int* a, int t) {
    for (int off = 1; off < 512; off <<= 1) {
        int v = (t >= off) ? a[t - off] : 0;
        __syncthreads();
        a[t] += v;
        __syncthreads();
    }
}
__device__ __forceinline__ void scan256(int* a, int t) {
    for (int off = 1; off < 256; off <<= 1) {
        int v = (t >= off) ? a[t - off] : 0;
        __syncthreads();
        a[t] += v;
        __syncthreads();
    }
}

// ------------------------------------------------ prep: cvt_w | p1_count
__global__ __launch_bounds__(256) void prep_kernel(
    const float* __restrict__ Ws1, const float* __restrict__ Wn1,
    const float* __restrict__ Ws2, const float* __restrict__ Wn2,
    unsigned short* __restrict__ W1f, unsigned short* __restrict__ W2f,
    const int* __restrict__ dst, int* __restrict__ counts, int E, int NB, int wB) {
    int tid = threadIdx.x;
    if (blockIdx.x < wB) {
        int i = blockIdx.x * 256 + tid;
        if (i < 128 * 256) {  // W1: MT=256, NCT=16
            int j = i & 7, L = (i >> 3) & 63, c = (i >> 9) & 15, kk = i >> 13;
            int k = kk * 32 + (L >> 4) * 8 + j;
            int col = c * 16 + (L & 15);
            float v = (col < 128) ? Ws1[k * 128 + col] : Wn1[k * 128 + (col - 128)];
            W1f[i] = f2bf(v);
        } else {
            int idx = i - 128 * 256;
            if (idx < 128 * 128) {  // W2: MT=128, NCT=8
                int j = idx & 7, L = (idx >> 3) & 63, c = (idx >> 9) & 7, kk = idx >> 12;
                int k = kk * 32 + (L >> 4) * 8 + j;
                int col = c * 16 + (L & 15);
                float v = (col < 64) ? Ws2[k * 64 + col] : Wn2[k * 64 + (col - 64)];
                W2f[idx] = f2bf(v);
            }
        }
    } else {
        __shared__ int hist[512];
        int blk = blockIdx.x - wB;
        int e0 = blk * P_EPB, e1 = min(e0 + P_EPB, E);
        for (int b = tid; b < 512; b += 256) hist[b] = 0;
        __syncthreads();
        for (int e = e0 + tid; e < e1; e += 256) atomicAdd(&hist[dst[e] >> BINSHIFT], 1);
        __syncthreads();
        for (int b = tid; b < NB; b += 256) counts[blk * NB + b] = hist[b];
    }
}

// ------------------------------------------------ p2a: per-bin scan over edge-blocks
__global__ __launch_bounds__(256) void p2a(const int* __restrict__ counts,
                                           int* __restrict__ segrel,
                                           int* __restrict__ tot, int NB, int NBLK) {
    __shared__ int s[256];
    int b = blockIdx.x, t = threadIdx.x;
    int v = (t < NBLK) ? counts[t * NB + b] : 0;
    s[t] = v;
    __syncthreads();
    scan256(s, t);
    if (t < NBLK) segrel[t * NB + b] = s[t] - v;
    if (t == 255) tot[b] = s[255];
}

// ------------------------------------------------ p3: LDS-binned scatter
// Edge record packed to 4B: (src << 9) | (dst & 511). src < 2^17, BINW=512.
__global__ __launch_bounds__(512) void p3_scatter(const int* __restrict__ src,
                                                  const int* __restrict__ dst,
                                                  const int* __restrict__ segrel,
                                                  const int* __restrict__ tot,
                                                  unsigned* __restrict__ epack,
                                                  int E, int NB) {
    __shared__ unsigned lp[P_EPB];
    __shared__ int hist[512];
    __shared__ int sBase[513];
    __shared__ int cursor[512];
    __shared__ int bbase[512];
    int t = threadIdx.x;
    int blk = blockIdx.x;
    int e0 = blk * P_EPB, e1 = min(e0 + P_EPB, E), m = e1 - e0;
    int tv = (t < NB) ? tot[t] : 0;
    bbase[t] = tv;
    __syncthreads();
    scan512(bbase, t);
    bbase[t] -= tv;  // exclusive bin base
    hist[t] = 0;
    __syncthreads();
    for (int e = e0 + t; e < e1; e += 512) atomicAdd(&hist[dst[e] >> BINSHIFT], 1);
    __syncthreads();
    int h = hist[t];
    scan512(hist, t);
    int excl = hist[t] - h;
    sBase[t] = excl;
    cursor[t] = excl;
    if (t == 0) sBase[512] = m;
    __syncthreads();
    for (int e = e0 + t; e < e1; e += 512) {
        int d = dst[e];
        int pos = atomicAdd(&cursor[d >> BINSHIFT], 1);
        lp[pos] = ((unsigned)src[e] << BINSHIFT) | ((unsigned)d & (BINW - 1));
    }
    __syncthreads();
    for (int i = t; i < m; i += 512) {
        int lo = 0, hi = NB;
        while (hi - lo > 1) {
            int mid = (lo + hi) >> 1;
            if (sBase[mid] <= i) lo = mid; else hi = mid;
        }
        epack[bbase[lo] + segrel[blk * NB + lo] + (i - sBase[lo])] = lp[i];
    }
}

// ------------------------------------------------ p4: per-bin CSR finalize
__global__ __launch_bounds__(512) void p4_csr(const unsigned* __restrict__ epack,
                                              const int* __restrict__ tot,
                                              int* __restrict__ row_start,
                                              int* __restrict__ cntg,
                                              float* __restrict__ inv_deg,
                                              int* __restrict__ csr_src, int N, int NB) {
    __shared__ int ncnt[512];
    __shared__ int cursor[512];
    __shared__ int bb[512];
    __shared__ int lsrc[LDS_CAP];
    int t = threadIdx.x;
    int b = blockIdx.x;
    int tv = (t < NB) ? tot[t] : 0;
    bb[t] = tv;
    __syncthreads();
    scan512(bb, t);
    int e1 = bb[b];           // inclusive: end of bin b
    int e0 = bb[b] - tot[b];  // exclusive: start of bin b
    int m = e1 - e0;
    int nbase = b << BINSHIFT;
    int nn = min(N - nbase, BINW);
    ncnt[t] = 0;
    __syncthreads();
    for (int i = e0 + t; i < e1; i += 512)
        atomicAdd(&ncnt[epack[i] & (BINW - 1)], 1);
    __syncthreads();
    int c = ncnt[t];
    scan512(ncnt, t);
    int excl = ncnt[t] - c;
    if (t < nn) {
        int node = nbase + t;
        row_start[node] = e0 + excl;
        cntg[node] = c;
        inv_deg[node] = 1.0f / fmaxf((float)c, 1.0f);
    }
    cursor[t] = excl;
    __syncthreads();
    for (int i = e0 + t; i < e1; i += 512) {
        unsigned v = epack[i];
        int pos = atomicAdd(&cursor[v & (BINW - 1)], 1);
        if (pos < LDS_CAP) lsrc[pos] = (int)(v >> BINSHIFT);
    }
    __syncthreads();
    int mm = min(m, LDS_CAP);
    for (int i = t; i < mm; i += 512) csr_src[e0 + i] = lsrc[i];
}

// ---------------------------------------------------------------- dual GEMM (MFMA bf16)
// Y = A[N,128] @ Wcat[128,MT].  A is bf16 (Ab) or fp32 (Af, AFP32: inline cvt).
//  cols [0,MSELF)  -> self output: bf16 (SELFBF) or fp32, row-major
//  cols [MSELF,MT) -> bf16 row-major Ynb (full-width gather rows)
// FUSEBN: A = BN+ReLU on-the-fly; sums is NREP-replicated [NREP][256].
template <int MT, int MSELF, bool SELFBF, bool FUSEBN, bool AFP32>
__global__ __launch_bounds__(256) void gemm_dual(const unsigned short* __restrict__ Ab,
                                                 const float* __restrict__ Af,
                                                 const unsigned short* __restrict__ Wf,
                                                 float* __restrict__ YselfF,
                                                 unsigned short* __restrict__ YselfB,
                                                 unsigned short* __restrict__ Ynb, int N,
                                                 const float* __restrict__ sums,
                                                 const float* __restrict__ gamma,
                                                 const float* __restrict__ beta,
                                                 float invN) {
    constexpr int K = 128;
    constexpr int NCT = MT / 16;
    constexpr int KS = K / 32;
    constexpr int MNB = MT - MSELF;
    __shared__ unsigned short Bl[KS * NCT * 64 * 8];
    __shared__ float ssc[128], ssh[128];

    for (int i = threadIdx.x; i < KS * NCT * 64; i += 256)
        ((short8*)Bl)[i] = ((const short8*)Wf)[i];
    if (FUSEBN && threadIdx.x < 128) {
        int c = threadIdx.x;
        float su = 0.f, sq = 0.f;
        for (int r = 0; r < NREP; r++) {
            su += sums[r * 256 + c];
            sq += sums[r * 256 + 128 + c];
        }
        float mu = su * invN;
        float var = sq * invN - mu * mu;
        float sc = gamma[c] * rsqrtf(var + EPS_BN);
        ssc[c] = sc;
        ssh[c] = beta[c] - mu * sc;
    }
    __syncthreads();

    int wv = threadIdx.x >> 6, lane = threadIdx.x & 63;
    int row0 = blockIdx.x * 128 + wv * 32;
    int m = lane & 15, quad = lane >> 4;

    short8 afrag[2][KS];
#pragma unroll
    for (int t = 0; t < 2; t++) {
        int arow = row0 + t * 16 + m;
        if (arow >= N) arow = N - 1;
#pragma unroll
        for (int kk = 0; kk < KS; kk++) {
            short8 raw;
            if (AFP32) {
                const float* ap = Af + (size_t)arow * K + quad * 8 + kk * 32;
                f32x4 a = *(const f32x4*)ap;
                f32x4 b = *(const f32x4*)(ap + 4);
#pragma unroll
                for (int j = 0; j < 4; j++) {
                    raw[j] = (short)f2bf(a[j]);
                    raw[4 + j] = (short)f2bf(b[j]);
                }
            } else {
                raw = *(const short8*)(Ab + (size_t)arow * K + quad * 8 + kk * 32);
            }
            if (FUSEBN) {
#pragma unroll
                for (int j = 0; j < 8; j++) {
                    int c = kk * 32 + quad * 8 + j;
                    float f = bf2f((unsigned short)raw[j]) * ssc[c] + ssh[c];
                    raw[j] = (short)f2bf(fmaxf(f, 0.f));
                }
            }
            afrag[t][kk] = raw;
        }
    }

    f32x4 acc[2][NCT];
#pragma unroll
    for (int t = 0; t < 2; t++)
        for (int c = 0; c < NCT; c++)
            for (int j = 0; j < 4; j++) acc[t][c][j] = 0.f;

#pragma unroll
    for (int kk = 0; kk < KS; kk++) {
#pragma unroll
        for (int c = 0; c < NCT; c++) {
            short8 bfrag = *(const short8*)&Bl[((kk * NCT + c) * 64 + lane) * 8];
#pragma unroll
            for (int t = 0; t < 2; t++)
                acc[t][c] = __builtin_amdgcn_mfma_f32_16x16x32_bf16(afrag[t][kk], bfrag,
                                                                    acc[t][c], 0, 0, 0);
        }
    }

    // C/D layout: col = lane&15, row = quad*4 + reg
#pragma unroll
    for (int t = 0; t < 2; t++) {
#pragma unroll
        for (int c = 0; c < NCT; c++) {
            int colg = c * 16 + m;
#pragma unroll
            for (int r = 0; r < 4; r++) {
                int row = row0 + t * 16 + quad * 4 + r;
                if (row < N) {
                    float v = acc[t][c][r];
                    if (colg < MSELF) {
                        if (SELFBF)
                            YselfB[(size_t)row * MSELF + colg] = f2bf(v);
                        else
                            YselfF[(size_t)row * MSELF + colg] = v;
                    } else {
                        Ynb[(size_t)row * MNB + (colg - MSELF)] = f2bf(v);
                    }
                }
            }
        }
    }
}

// ------------------------------------------------- aggregation + fused BN stats
// Layer 1: one wave per node (persistent); 64 lanes x uint = full 256B row/edge;
// 8-edge unroll. Self bf16 in, h1 bf16 out. Stats -> LDS -> replicated atomics
// (replica blockIdx & 31: 2048 blocks / 32 reps = 64 same-address atomics).
__global__ __launch_bounds__(256) void agg_row128(const unsigned int* __restrict__ Sb,
                                                  const unsigned int* __restrict__ T,
                                                  const int* __restrict__ row_start,
                                                  const int* __restrict__ cnt,
                                                  const float* __restrict__ inv_deg,
                                                  const int* __restrict__ csr_src,
                                                  const float* __restrict__ bias,
                                                  unsigned int* __restrict__ Out,
                                                  float* __restrict__ sums,
                                                  int N, int totalWaves) {
    int wv = threadIdx.x >> 6, lane = threadIdx.x & 63;
    int c = lane * 2;
    float bs0 = bias[c], bs1 = bias[c + 1];
    float S0 = 0.f, S1 = 0.f, Q0 = 0.f, Q1 = 0.f;
    for (int n = blockIdx.x * 4 + wv; n < N; n += totalWaves) {
        int start = row_start[n];
        int ec = cnt[n];
        float inv = inv_deg[n];
        float a0 = 0.f, a1 = 0.f;
        int e = 0;
        for (; e + 7 < ec; e += 8) {
            int i0 = csr_src[start + e];
            int i1 = csr_src[start + e + 1];
            int i2 = csr_src[start + e + 2];
            int i3 = csr_src[start + e + 3];
            int i4 = csr_src[start + e + 4];
            int i5 = csr_src[start + e + 5];
            int i6 = csr_src[start + e + 6];
            int i7 = csr_src[start + e + 7];
            unsigned u0 = T[(size_t)i0 * 64 + lane];
            unsigned u1 = T[(size_t)i1 * 64 + lane];
            unsigned u2 = T[(size_t)i2 * 64 + lane];
            unsigned u3 = T[(size_t)i3 * 64 + lane];
            unsigned u4 = T[(size_t)i4 * 64 + lane];
            unsigned u5 = T[(size_t)i5 * 64 + lane];
            unsigned u6 = T[(size_t)i6 * 64 + lane];
            unsigned u7 = T[(size_t)i7 * 64 + lane];
            a0 += bflo(u0) + bflo(u1) + bflo(u2) + bflo(u3) +
                  bflo(u4) + bflo(u5) + bflo(u6) + bflo(u7);
            a1 += bfhi(u0) + bfhi(u1) + bfhi(u2) + bfhi(u3) +
                  bfhi(u4) + bfhi(u5) + bfhi(u6) + bfhi(u7);
        }
        for (; e < ec; e++) {
            unsigned u0 = T[(size_t)csr_src[start + e] * 64 + lane];
            a0 += bflo(u0);
            a1 += bfhi(u0);
        }
        unsigned su = Sb[(size_t)n * 64 + lane];
        float h0 = bflo(su) + a0 * inv + bs0;
        float h1 = bfhi(su) + a1 * inv + bs1;
        Out[(size_t)n * 64 + lane] = (unsigned)f2bf(h0) | ((unsigned)f2bf(h1) << 16);
        S0 += h0; Q0 += h0 * h0;
        S1 += h1; Q1 += h1 * h1;
    }
    __shared__ float ls[256];
    ls[threadIdx.x] = 0.f;
    __syncthreads();
    atomicAdd(&ls[c], S0);
    atomicAdd(&ls[c + 1], S1);
    atomicAdd(&ls[128 + c], Q0);
    atomicAdd(&ls[129 + c], Q1);
    __syncthreads();
    float* dstS = sums + (size_t)(blockIdx.x & (NREP - 1)) * 256;
    atomicAdd(&dstS[threadIdx.x], ls[threadIdx.x]);
}

// Layer 2: two 32-lane groups per wave (persistent); uint/lane = full 128B row;
// 4-edge unroll. Self fp32 in d_out, in-place. Replicated stats.
__global__ __launch_bounds__(256) void agg_row64(const unsigned int* __restrict__ T,
                                                 const int* __restrict__ row_start,
                                                 const int* __restrict__ cnt,
                                                 const float* __restrict__ inv_deg,
                                                 const int* __restrict__ csr_src,
                                                 const float* __restrict__ bias,
                                                 float* Self, float* __restrict__ sums,
                                                 int N, int totalHalf) {
    int wv = threadIdx.x >> 6, L = threadIdx.x & 63;
    int g = L >> 5, h = L & 31;
    int c = h * 2;
    float bs0 = bias[c], bs1 = bias[c + 1];
    float S0 = 0.f, S1 = 0.f, Q0 = 0.f, Q1 = 0.f;
    for (int n = (blockIdx.x * 4 + wv) * 2 + g; n < N; n += totalHalf) {
        int start = row_start[n];
        int ec = cnt[n];
        float inv = inv_deg[n];
        float a0 = 0.f, a1 = 0.f;
        int e = 0;
        for (; e + 3 < ec; e += 4) {
            int i0 = csr_src[start + e];
            int i1 = csr_src[start + e + 1];
            int i2 = csr_src[start + e + 2];
            int i3 = csr_src[start + e + 3];
            unsigned u0 = T[(size_t)i0 * 32 + h];
            unsigned u1 = T[(size_t)i1 * 32 + h];
            unsigned u2 = T[(size_t)i2 * 32 + h];
            unsigned u3 = T[(size_t)i3 * 32 + h];
            a0 += bflo(u0) + bflo(u1) + bflo(u2) + bflo(u3);
            a1 += bfhi(u0) + bfhi(u1) + bfhi(u2) + bfhi(u3);
        }
        for (; e < ec; e++) {
            unsigned u0 = T[(size_t)csr_src[start + e] * 32 + h];
            a0 += bflo(u0);
            a1 += bfhi(u0);
        }
        size_t off = (size_t)n * 64 + c;
        float h0 = Self[off] + a0 * inv + bs0;
        float h1 = Self[off + 1] + a1 * inv + bs1;
        Self[off] = h0;
        Self[off + 1] = h1;
        S0 += h0; Q0 += h0 * h0;
        S1 += h1; Q1 += h1 * h1;
    }
    __shared__ float ls[128];
    if (threadIdx.x < 128) ls[threadIdx.x] = 0.f;
    __syncthreads();
    atomicAdd(&ls[c], S0);
    atomicAdd(&ls[c + 1], S1);
    atomicAdd(&ls[64 + c], Q0);
    atomicAdd(&ls[65 + c], Q1);
    __syncthreads();
    if (threadIdx.x < 128) {
        float* dstS = sums + (size_t)(blockIdx.x & (NREP - 1)) * 128;
        atomicAdd(&dstS[threadIdx.x], ls[threadIdx.x]);
    }
}

// layer-2 apply (finalize folded, NREP-replicated sums): fp32 in-place, no ReLU
__global__ __launch_bounds__(256) void bn_apply_f64(float* H, const float* __restrict__ sums,
                                                    const float* __restrict__ gamma,
                                                    const float* __restrict__ beta,
                                                    int N, float invN) {
    __shared__ float ss[128];
    int tid = threadIdx.x;
    if (tid < 64) {
        float su = 0.f, sq = 0.f;
        for (int r = 0; r < NREP; r++) {
            su += sums[r * 128 + tid];
            sq += sums[r * 128 + 64 + tid];
        }
        float mu = su * invN;
        float var = sq * invN - mu * mu;
        float sc = gamma[tid] * rsqrtf(var + EPS_BN);
        ss[tid] = sc;
        ss[64 + tid] = beta[tid] - mu * sc;
    }
    __syncthreads();
    int total4 = N * 16;
    float4* H4 = (float4*)H;
    for (int i = blockIdx.x * 256 + threadIdx.x; i < total4; i += 256 * gridDim.x) {
        int c0 = (i * 4) & 63;
        float4 v = H4[i];
        float4 sc = *(const float4*)&ss[c0];
        float4 sh = *(const float4*)&ss[64 + c0];
        v.x = v.x * sc.x + sh.x;
        v.y = v.y * sc.y + sh.y;
        v.z = v.z * sc.z + sh.z;
        v.w = v.w * sc.w + sh.w;
        H4[i] = v;
    }
}

// ---------------------------------------------------------------- launch
extern "C" void kernel_launch(void* const* d_in, const int* in_sizes, int n_in,
                              void* d_out, int out_size, void* d_ws, size_t ws_size,
                              hipStream_t stream) {
    const float* X = (const float*)d_in[0];
    const int* src = (const int*)d_in[1];
    const int* dst = (const int*)d_in[2];
    const float* Wself1 = (const float*)d_in[3];
    const float* Wneigh1 = (const float*)d_in[4];
    const float* b1 = (const float*)d_in[5];
    const float* g1 = (const float*)d_in[6];
    const float* be1 = (const float*)d_in[7];
    const float* Wself2 = (const float*)d_in[8];
    const float* Wneigh2 = (const float*)d_in[9];
    const float* b2 = (const float*)d_in[10];
    const float* g2 = (const float*)d_in[11];
    const float* be2 = (const float*)d_in[12];
    float* out = (float*)d_out;

    const int N = in_sizes[0] / 128;
    const int E = in_sizes[1];
    const int NB = (N + BINW - 1) >> BINSHIFT;    // 196
    const int NBLK = (E + P_EPB - 1) / P_EPB;     // 196 (<=256 required by p2a)

    char* p = (char*)d_ws;
    auto carve = [&](size_t bytes) {
        char* r = p;
        p += (bytes + 255) & ~(size_t)255;
        return r;
    };
    float* sums1 = (float*)carve((size_t)NREP * 256 * 4);
    float* sums2 = (float*)carve((size_t)NREP * 128 * 4);
    size_t zero_bytes = (size_t)(p - (char*)d_ws);
    int* counts = (int*)carve((size_t)NBLK * NB * 4);
    int* segrel = (int*)carve((size_t)NBLK * NB * 4);
    int* tot = (int*)carve((size_t)NB * 4);
    unsigned* epack = (unsigned*)carve((size_t)E * 4);
    int* csr_src = (int*)carve((size_t)E * 4);
    int* row_start = (int*)carve((size_t)N * 4);
    int* cntg = (int*)carve((size_t)N * 4);
    float* inv_deg = (float*)carve((size_t)N * 4);
    unsigned short* W1f = (unsigned short*)carve(128 * 256 * 2);
    unsigned short* W2f = (unsigned short*)carve(128 * 128 * 2);
    unsigned short* bufS = (unsigned short*)carve((size_t)N * 128 * 2);  // self1 bf16
    unsigned short* tab = (unsigned short*)carve((size_t)N * 128 * 2);   // row-major
    unsigned short* h1b = (unsigned short*)carve((size_t)N * 128 * 2);   // h1 pre-BN bf16

    hipMemsetAsync(d_ws, 0, zero_bytes, stream);

    const int wB = 192;
    const float invN = 1.0f / (float)N;
    prep_kernel<<<wB + NBLK, 256, 0, stream>>>(Wself1, Wneigh1, Wself2, Wneigh2, W1f, W2f,
                                               dst, counts, E, NB, wB);
    p2a<<<NB, 256, 0, stream>>>(counts, segrel, tot, NB, NBLK);
    p3_scatter<<<NBLK, 512, 0, stream>>>(src, dst, segrel, tot, epack, E, NB);
    p4_csr<<<NB, 512, 0, stream>>>(epack, tot, row_start, cntg, inv_deg, csr_src, N, NB);

    int ggrid = (N + 127) / 128;
    // ---- layer 1 (128 -> 128): fp32 X in (inline cvt), self bf16, neigh bf16
    gemm_dual<256, 128, true, false, true><<<ggrid, 256, 0, stream>>>(
        nullptr, X, W1f, nullptr, bufS, tab, N, nullptr, nullptr, nullptr, 0.f);
    agg_row128<<<2048, 256, 0, stream>>>(
        (const unsigned int*)bufS, (const unsigned int*)tab, row_start, cntg, inv_deg,
        csr_src, b1, (unsigned int*)h1b, sums1, N, 8192);

    // ---- layer 2 (128 -> 64): BN1+ReLU fused into A-load; self fp32 -> out
    gemm_dual<128, 64, false, true, false><<<ggrid, 256, 0, stream>>>(
        h1b, nullptr, W2f, out, nullptr, tab, N, sums1, g1, be1, invN);
    agg_row64<<<2048, 256, 0, stream>>>(
        (const unsigned int*)tab, row_start, cntg, inv_deg, csr_src, b2, out, sums2,
        N, 16384);
    bn_apply_f64<<<2048, 256, 0, stream>>>(out, sums2, g2, be2, N, invN);
}